// Round 15
// baseline (1148.737 us; speedup 1.0000x reference)
//
#include <hip/hip_runtime.h>
#include <hip/hip_bf16.h>

#define NN 30000
#define NE 480000
#define ADL 2.8332133440562162f   // ln(17)

typedef unsigned int u32;
typedef unsigned short u16;

typedef _Float16 half2v __attribute__((ext_vector_type(2)));

__device__ __forceinline__ u16 f2h(float f){
  union { _Float16 h; u16 u; } v; v.h = (_Float16)f; return v.u;
}
__device__ __forceinline__ u32 pack2(float lo, float hi){
  return (u32)f2h(lo) | ((u32)f2h(hi) << 16);
}
__device__ __forceinline__ float dot2f(u32 a, u32 b, float c){
#if defined(__has_builtin) && __has_builtin(__builtin_amdgcn_fdot2)
  union U { u32 u; half2v h; };
  U ua, ub; ua.u = a; ub.u = b;
  return __builtin_amdgcn_fdot2(ua.h, ub.h, c, false);
#else
  float r;
  asm("v_dot2_f32_f16 %0, %1, %2, %3" : "=v"(r) : "v"(a), "v"(b), "v"(c));
  return r;
#endif
}

// ======================= CSR build =======================
__global__ void k_hist(const int* __restrict__ ei, int* __restrict__ cnt){
  int e = blockIdx.x * blockDim.x + threadIdx.x;
  if (e < NE) atomicAdd(&cnt[ei[NE + e]], 1);
}

// hierarchical scan (validated R13)
__global__ __launch_bounds__(1024) void k_scanA(const int* __restrict__ cnt,
                                                int* __restrict__ off, int* __restrict__ bsum){
  __shared__ int buf[1024];
  const int b = blockIdx.x, tid = threadIdx.x;
  const int i = b*1024 + tid;
  int v = (i < NN) ? cnt[i] : 0;
  buf[tid] = v;
  __syncthreads();
  for (int s = 1; s < 1024; s <<= 1){
    int t = (tid >= s) ? buf[tid - s] : 0;
    __syncthreads();
    buf[tid] += t;
    __syncthreads();
  }
  if (i < NN) off[i] = buf[tid] - v;
  if (tid == 1023) bsum[b] = buf[1023];
}

__global__ void k_scanB(int* __restrict__ bsum){
  if (threadIdx.x == 0 && blockIdx.x == 0){
    int acc = 0;
    for (int b = 0; b < 30; ++b){ int v = bsum[b]; bsum[b] = acc; acc += v; }
  }
}

__global__ void k_scanC(int* __restrict__ off, const int* __restrict__ bsum){
  int i = blockIdx.x * blockDim.x + threadIdx.x;
  if (i < NN) off[i] += bsum[i >> 10];
  if (i == NN) off[NN] = NE;
}

__global__ void k_scatter(const int* __restrict__ ei, const int* __restrict__ off,
                          int* __restrict__ cursor, int* __restrict__ eids,
                          int* __restrict__ sidC){
  int e = blockIdx.x * blockDim.x + threadIdx.x;
  if (e < NE){
    int d = ei[NE + e];
    int pos = off[d] + atomicAdd(&cursor[d], 1);
    eids[pos] = e;
    sidC[pos] = ei[e];     // CSR-ordered src ids
  }
}

// ======================= x pre-pack: f32 row -> packed half2 =======================
__global__ void k_packx(const float* __restrict__ x, u32* __restrict__ xH){
  int i = blockIdx.x * blockDim.x + threadIdx.x;
  if (i < NN * 64){
    const float2 v = *(const float2*)(x + (size_t)i * 2);
    xH[i] = pack2(v.x, v.y);
  }
}

// ======================= weight prep =======================
__global__ void k_prep(const float* __restrict__ preW0, const float* __restrict__ preW1,
                       const float* __restrict__ postW0, const float* __restrict__ postW1,
                       const float* __restrict__ Wlin,
                       u32* __restrict__ preW0H, u32* __restrict__ preW1H,
                       float* __restrict__ postW0T, float* __restrict__ postW1T,
                       float* __restrict__ WlinT)
{
  int i = blockIdx.x * blockDim.x + threadIdx.x;
  if (i < 65536){ int c = i >> 9, kk = i & 511;
    postW0T[i] = postW0[(c >> 5)*16384 + kk*32 + (c & 31)]; }
  if (i < 6144){          // preW0H[c][q]: pair (k=2q, k=2q+1) of preW0[t][k][f]
    int c = i / 48, q = i % 48;
    int t = c >> 5, f = c & 31;
    preW0H[i] = pack2(preW0[t*3072 + (2*q)*32 + f], preW0[t*3072 + (2*q+1)*32 + f]);
  }
  if (i < 2048){          // preW1H[c][q]: pair (g=2q, g=2q+1) of preW1[t][g][f]
    int c = i / 16, q = i % 16;
    int t = c >> 5, f = c & 31;
    preW1H[i] = pack2(preW1[t*1024 + (2*q)*32 + f], preW1[t*1024 + (2*q+1)*32 + f]);
  }
  if (i < 4096){ int c = i >> 5, g = i & 31;
    postW1T[i] = postW1[(c >> 5)*1024 + g*32 + (c & 31)]; }
  if (i < 16384){ int c = i >> 7, k = i & 127; WlinT[i] = Wlin[k*128 + c]; }
}

// ======================= ea precompute, CSR-ordered, f16 output =======================
__global__ __launch_bounds__(256) void k_ea(const float* __restrict__ eattr,
                                            const float* __restrict__ Wedge,
                                            const float* __restrict__ b_edge,
                                            const int* __restrict__ eids,
                                            u16* __restrict__ eaH)
{
  __shared__ float WS[512];
  __shared__ float bS[32];
  const int tid = threadIdx.x;
  WS[tid]       = Wedge[tid];
  WS[tid + 256] = Wedge[tid + 256];
  if (tid < 32) bS[tid] = b_edge[tid];
  __syncthreads();
  const int g = tid & 31;
  const int pos = blockIdx.x * 8 + (tid >> 5);
  if (pos < NE){
    const int e = eids[pos];
    const float* ar = eattr + (size_t)e * 16;
    float acc = bS[g];
    #pragma unroll
    for (int ii = 0; ii < 16; ++ii) acc = fmaf(ar[ii], WS[ii*32 + g], acc);
    eaH[(size_t)pos*32 + g] = f2h(acc);
  }
}

// ======================= edge phase (R14 structure; launch_bounds (128,4) for occupancy) =======================
// R14: VALUBusy 46% @ occupancy 19.6% — latency-bound with waves artificially limited by
// __launch_bounds__(128,2). VGPR=100 fits the (128,4) 128-reg cap -> double resident waves.
__global__ __launch_bounds__(128, 4) void k_edge4(
  const u32* __restrict__ xHu,
  const u32* __restrict__ eaHu,
  const int* __restrict__ sidC,
  const u32* __restrict__ preW0H, const u32* __restrict__ preW1H,
  const float* __restrict__ pre_b0, const float* __restrict__ pre_b1,
  const int* __restrict__ off,
  float* __restrict__ agg)
{
  const int c = threadIdx.x;        // channel 0..127
  const int t = c >> 5;             // tower

  __shared__ __align__(16) u32 xdH[64];           // dst-x packed pairs
  __shared__ __align__(16) u32 xsH[2][4][64];     // [buf][edge-in-group][pair]
  __shared__ __align__(16) u32 eaS[2][4][16];
  __shared__ __align__(16) u32 hP[4][64];         // wave-local h (u32 both ways)
  __shared__ int sidS[64];

  u32 w0p[48], w1p[16];
  #pragma unroll
  for (int q = 0; q < 12; ++q) *(uint4*)&w0p[q*4] = *(const uint4*)(preW0H + (size_t)c*48 + q*4);
  #pragma unroll
  for (int q = 0; q < 4; ++q)  *(uint4*)&w1p[q*4] = *(const uint4*)(preW1H + (size_t)c*16 + q*4);
  const float pb0 = pre_b0[c];
  const float pb1 = pre_b1[c];

  const int el = c >> 6;            // this thread stages edges el and el+2
  const int eh = el + 2;
  const int col = c & 63;

  for (int nn = 0; nn < 8; ++nn){
    const int n = blockIdx.x * 8 + nn;
    __syncthreads();                 // protect xdH + buffers from previous node
    if (c < 64) xdH[c] = xHu[(size_t)n*64 + c];
    const int e0 = off[n], e1 = off[n+1];
    float sum = 0.f, sq = 0.f;
    float mn = __builtin_inff(), mx = -__builtin_inff();

    for (int base = e0; base < e1; base += 64){
      const int nv = min(64, e1 - base);
      if (c < nv) sidS[c] = sidC[base + c];
      __syncthreads();               // sidS + xdH visible

      // dst-slice dot: identical for every edge of this node — once per window
      float a0n = pb0;
      #pragma unroll
      for (int i4 = 0; i4 < 4; ++i4){
        const uint4 xv = *(const uint4*)&xdH[t*16 + i4*4];
        a0n = dot2f(xv.x, w0p[i4*4+0], a0n);
        a0n = dot2f(xv.y, w0p[i4*4+1], a0n);
        a0n = dot2f(xv.z, w0p[i4*4+2], a0n);
        a0n = dot2f(xv.w, w0p[i4*4+3], a0n);
      }

      const int np = (nv + 3) >> 2;

      // prologue: stage group 0 into buf 0
      {
        const int g0 = min(el, nv-1), g1 = min(eh, nv-1);
        xsH[0][el][col] = xHu[(size_t)sidS[g0]*64 + col];
        xsH[0][eh][col] = xHu[(size_t)sidS[g1]*64 + col];
        if (c < 64){
          const int e = c >> 4, q = c & 15;
          eaS[0][e][q] = eaHu[(size_t)(base + min(e, nv-1))*16 + q];
        }
      }
      __syncthreads();

      for (int p = 0; p < np; ++p){
        const int buf = p & 1;
        const int sub = p * 4;
        const bool hasNext = (p + 1 < np);     // block-uniform branch

        // issue next-group global loads into registers (latency hides under compute)
        u32 nxs0 = 0, nxs1 = 0, nea = 0;
        if (hasNext){
          const int s2 = sub + 4;
          const int g0 = min(s2 + el, nv-1), g1 = min(s2 + eh, nv-1);
          nxs0 = xHu[(size_t)sidS[g0]*64 + col];
          nxs1 = xHu[(size_t)sidS[g1]*64 + col];
          if (c < 64){
            const int e = c >> 4, q = c & 15;
            nea = eaHu[(size_t)(base + min(s2 + e, nv-1))*16 + q];
          }
        }

        // layer0 for 4 edges: b128 activation loads into regs, dot2 from regs
        float aXs[4] = {0,0,0,0}, aEa[4] = {0,0,0,0};
        #pragma unroll
        for (int i4 = 0; i4 < 4; ++i4){
          uint4 xsv[4], eav[4];
          #pragma unroll
          for (int e = 0; e < 4; ++e){
            xsv[e] = *(const uint4*)&xsH[buf][e][t*16 + i4*4];
            eav[e] = *(const uint4*)&eaS[buf][e][i4*4];
          }
          const u32 wx0 = w0p[16+i4*4+0], wx1 = w0p[16+i4*4+1];
          const u32 wx2 = w0p[16+i4*4+2], wx3 = w0p[16+i4*4+3];
          const u32 we0 = w0p[32+i4*4+0], we1 = w0p[32+i4*4+1];
          const u32 we2 = w0p[32+i4*4+2], we3 = w0p[32+i4*4+3];
          #pragma unroll
          for (int e = 0; e < 4; ++e){
            aXs[e] = dot2f(xsv[e].x, wx0, aXs[e]);
            aXs[e] = dot2f(xsv[e].y, wx1, aXs[e]);
            aXs[e] = dot2f(xsv[e].z, wx2, aXs[e]);
            aXs[e] = dot2f(xsv[e].w, wx3, aXs[e]);
            aEa[e] = dot2f(eav[e].x, we0, aEa[e]);
            aEa[e] = dot2f(eav[e].y, we1, aEa[e]);
            aEa[e] = dot2f(eav[e].z, we2, aEa[e]);
            aEa[e] = dot2f(eav[e].w, we3, aEa[e]);
          }
        }
        // pack h pairwise (u32-typed store; even lanes write word (c, c+1))
        #pragma unroll
        for (int e = 0; e < 4; ++e){
          const float h = fmaxf(a0n + aXs[e] + aEa[e], 0.f);
          const u32 mine = (u32)f2h(h);
          const u32 oth  = (u32)__shfl_xor((int)mine, 1);
          if ((c & 1) == 0) hP[e][c >> 1] = mine | (oth << 16);
        }

        // layer1 for 4 edges (b128 hP loads; within-wave, no barrier needed)
        float mm[4] = {pb1, pb1, pb1, pb1};
        #pragma unroll
        for (int i4 = 0; i4 < 4; ++i4){
          uint4 hv[4];
          #pragma unroll
          for (int e = 0; e < 4; ++e) hv[e] = *(const uint4*)&hP[e][t*16 + i4*4];
          const u32 w0v = w1p[i4*4+0], w1v = w1p[i4*4+1];
          const u32 w2v = w1p[i4*4+2], w3v = w1p[i4*4+3];
          #pragma unroll
          for (int e = 0; e < 4; ++e){
            mm[e] = dot2f(hv[e].x, w0v, mm[e]);
            mm[e] = dot2f(hv[e].y, w1v, mm[e]);
            mm[e] = dot2f(hv[e].z, w2v, mm[e]);
            mm[e] = dot2f(hv[e].w, w3v, mm[e]);
          }
        }
        #pragma unroll
        for (int e = 0; e < 4; ++e){
          if (sub + e < nv){
            sum += mm[e]; sq = fmaf(mm[e], mm[e], sq);
            mn = fminf(mn, mm[e]); mx = fmaxf(mx, mm[e]);
          }
        }

        // write staged regs into the other buffer (no conflict with buf reads)
        if (hasNext){
          xsH[buf^1][el][col] = nxs0;
          xsH[buf^1][eh][col] = nxs1;
          if (c < 64){ const int e = c >> 4, q = c & 15; eaS[buf^1][e][q] = nea; }
        }
        __syncthreads();               // single barrier per 4-edge group
      }
    }

    const int deg = e1 - e0;
    const size_t b = (size_t)n * 512;
    agg[b + c]       = sum;
    agg[b + 128 + c] = sq;
    agg[b + 256 + c] = (deg > 0) ? mn : 0.f;
    agg[b + 384 + c] = (deg > 0) ? mx : 0.f;
  }
}

// ======================= node phase: G=12 nodes/block, register-tiled =======================
__global__ __launch_bounds__(128, 2) void k_post(
  const float* __restrict__ x, const float* __restrict__ agg,
  const int* __restrict__ off,
  const float* __restrict__ postW0T, const float* __restrict__ postW1T,
  const float* __restrict__ WlinT,
  const float* __restrict__ post_b0, const float* __restrict__ post_b1,
  const float* __restrict__ b_lin, const float* __restrict__ ln_g,
  const float* __restrict__ ln_b,
  float* __restrict__ out)
{
  const int c = threadIdx.x;
  const int t = c >> 5;
  const int n0 = blockIdx.x * 12;

  __shared__ __align__(16) float aS[12][768];
  __shared__ __align__(16) float hpS[12][128];
  __shared__ __align__(16) float vS[12][128];
  __shared__ float s1S[12], s2S[12], muS[12], rsS[12];

  #pragma unroll
  for (int n = 0; n < 12; ++n){
    const size_t nb = (size_t)(n0 + n);
    aS[n][c] = x[nb*128 + c];
    float sum = agg[nb*512 + c];
    float sq  = agg[nb*512 + 128 + c];
    float mnv = agg[nb*512 + 256 + c];
    float mxv = agg[nb*512 + 384 + c];
    int deg = off[n0+n+1] - off[n0+n];
    float denom = fmaxf((float)deg, 1.f);
    float mean = sum / denom;
    float sd = sqrtf(fmaxf(sq/denom - mean*mean, 0.f) + 1e-5f);
    aS[n][128 + c] = sum;  aS[n][256 + c] = mean;
    aS[n][384 + c] = mnv;  aS[n][512 + c] = mxv;  aS[n][640 + c] = sd;
  }
  if (c < 12){
    int deg = off[n0+c+1] - off[n0+c];
    float logd = logf(fmaxf((float)deg, 1.f) + 1.f);
    s1S[c] = logd / ADL; s2S[c] = ADL / logd;
  }
  __syncthreads();

  float acc[12], pa1[12], pa2[12];
  const float pb0 = post_b0[c];
  #pragma unroll
  for (int n = 0; n < 12; ++n){ acc[n] = pb0; pa1[n] = 0.f; pa2[n] = 0.f; }
  const float* Wp = postW0T + (size_t)c * 512;
  #pragma unroll
  for (int k4 = 0; k4 < 8; ++k4){
    float4 w = *(const float4*)(Wp + k4*4);
    #pragma unroll
    for (int n = 0; n < 12; ++n){
      float4 a = *(const float4*)&aS[n][t*32 + k4*4];
      acc[n] = fmaf(a.x, w.x, acc[n]); acc[n] = fmaf(a.y, w.y, acc[n]);
      acc[n] = fmaf(a.z, w.z, acc[n]); acc[n] = fmaf(a.w, w.w, acc[n]);
    }
  }
  for (int a = 0; a < 5; ++a){
    #pragma unroll
    for (int k4 = 0; k4 < 8; ++k4){
      float4 w0v = *(const float4*)(Wp + 32  + a*32 + k4*4);
      float4 w1v = *(const float4*)(Wp + 192 + a*32 + k4*4);
      float4 w2v = *(const float4*)(Wp + 352 + a*32 + k4*4);
      #pragma unroll
      for (int n = 0; n < 12; ++n){
        float4 av = *(const float4*)&aS[n][128 + a*128 + t*32 + k4*4];
        acc[n] = fmaf(av.x, w0v.x, acc[n]); acc[n] = fmaf(av.y, w0v.y, acc[n]);
        acc[n] = fmaf(av.z, w0v.z, acc[n]); acc[n] = fmaf(av.w, w0v.w, acc[n]);
        pa1[n] = fmaf(av.x, w1v.x, pa1[n]); pa1[n] = fmaf(av.y, w1v.y, pa1[n]);
        pa1[n] = fmaf(av.z, w1v.z, pa1[n]); pa1[n] = fmaf(av.w, w1v.w, pa1[n]);
        pa2[n] = fmaf(av.x, w2v.x, pa2[n]); pa2[n] = fmaf(av.y, w2v.y, pa2[n]);
        pa2[n] = fmaf(av.z, w2v.z, pa2[n]); pa2[n] = fmaf(av.w, w2v.w, pa2[n]);
      }
    }
  }
  #pragma unroll
  for (int n = 0; n < 12; ++n)
    hpS[n][c] = fmaxf(acc[n] + s1S[n]*pa1[n] + s2S[n]*pa2[n], 0.f);
  __syncthreads();

  float w1r[32];
  #pragma unroll
  for (int q = 0; q < 8; ++q) *(float4*)&w1r[q*4] = *(const float4*)(postW1T + (size_t)c*32 + q*4);
  float a2[12];
  const float pb1v = post_b1[c];
  #pragma unroll
  for (int n = 0; n < 12; ++n) a2[n] = pb1v;
  #pragma unroll
  for (int g4 = 0; g4 < 8; ++g4){
    #pragma unroll
    for (int n = 0; n < 12; ++n){
      float4 h = *(const float4*)&hpS[n][t*32 + g4*4];
      a2[n] = fmaf(h.x, w1r[g4*4+0], a2[n]); a2[n] = fmaf(h.y, w1r[g4*4+1], a2[n]);
      a2[n] = fmaf(h.z, w1r[g4*4+2], a2[n]); a2[n] = fmaf(h.w, w1r[g4*4+3], a2[n]);
    }
  }
  #pragma unroll
  for (int n = 0; n < 12; ++n) vS[n][c] = a2[n];
  __syncthreads();

  float a3[12];
  const float blv = b_lin[c];
  #pragma unroll
  for (int n = 0; n < 12; ++n) a3[n] = blv;
  const float* Wl = WlinT + (size_t)c * 128;
  #pragma unroll 8
  for (int k4 = 0; k4 < 32; ++k4){
    float4 w = *(const float4*)(Wl + k4*4);
    #pragma unroll
    for (int n = 0; n < 12; ++n){
      float4 v = *(const float4*)&vS[n][k4*4];
      a3[n] = fmaf(v.x, w.x, a3[n]); a3[n] = fmaf(v.y, w.y, a3[n]);
      a3[n] = fmaf(v.z, w.z, a3[n]); a3[n] = fmaf(v.w, w.w, a3[n]);
    }
  }

  #pragma unroll
  for (int n = 0; n < 12; ++n) hpS[n][c] = a3[n];
  __syncthreads();
  {
    const int n = c >> 3, seg = c & 7;
    if (n < 12){
      float ps = 0.f, ps2 = 0.f;
      #pragma unroll
      for (int k = 0; k < 16; ++k){
        float v = hpS[n][seg*16 + k];
        ps += v; ps2 = fmaf(v, v, ps2);
      }
      ps += __shfl_xor(ps, 1); ps2 += __shfl_xor(ps2, 1);
      ps += __shfl_xor(ps, 2); ps2 += __shfl_xor(ps2, 2);
      ps += __shfl_xor(ps, 4); ps2 += __shfl_xor(ps2, 4);
      if (seg == 0){
        float mu = ps * (1.f/128.f);
        float var = fmaxf(ps2 * (1.f/128.f) - mu*mu, 0.f);
        muS[n] = mu; rsS[n] = rsqrtf(var + 1e-5f);
      }
    }
  }
  __syncthreads();
  const float gv = ln_g[c], bv = ln_b[c];
  #pragma unroll
  for (int n = 0; n < 12; ++n){
    float o = aS[n][c] + fmaxf((a3[n] - muS[n])*rsS[n]*gv + bv, 0.f);
    out[(size_t)(n0 + n)*128 + c] = o;
  }
}

// ======================= fallback: proven monolithic kernel (R3, f32) =======================
__global__ __launch_bounds__(128) void k_mono(
  const float* __restrict__ x, const int* __restrict__ ei,
  const float* __restrict__ eattr,
  const float* __restrict__ Wedge, const float* __restrict__ b_edge,
  const float* __restrict__ preW0, const float* __restrict__ pre_b0,
  const float* __restrict__ preW1, const float* __restrict__ pre_b1,
  const float* __restrict__ postW0, const float* __restrict__ post_b0,
  const float* __restrict__ postW1, const float* __restrict__ post_b1,
  const float* __restrict__ Wlin, const float* __restrict__ b_lin,
  const float* __restrict__ ln_g, const float* __restrict__ ln_b,
  const int* __restrict__ off, const int* __restrict__ eids,
  float* __restrict__ out)
{
  const int n = blockIdx.x;
  const int c = threadIdx.x;
  const int t = c >> 5, f = c & 31;
  __shared__ float xdS[128], xsS[128], eaS[32], hS[128];
  __shared__ float aggS[5][128], hpS[128], vS[128], red[4];

  const float xd = x[(size_t)n*128 + c];
  xdS[c] = xd;
  const int e0 = off[n], e1 = off[n+1];
  const int deg = e1 - e0;
  float sum = 0.f, sq = 0.f, mn = __builtin_inff(), mx = -__builtin_inff();
  __syncthreads();

  for (int idx = e0; idx < e1; ++idx){
    const int e = eids[idx];
    const int s = ei[e];
    xsS[c] = x[(size_t)s*128 + c];
    if (c < 32){
      float acc = b_edge[c];
      #pragma unroll
      for (int ii = 0; ii < 16; ++ii) acc = fmaf(eattr[(size_t)e*16 + ii], Wedge[ii*32 + c], acc);
      eaS[c] = acc;
    }
    __syncthreads();
    float acc = pre_b0[c];
    const float* W0 = preW0 + t*3072 + f;
    #pragma unroll 8
    for (int k = 0; k < 32; ++k) acc = fmaf(xdS[t*32+k], W0[k*32], acc);
    #pragma unroll 8
    for (int k = 0; k < 32; ++k) acc = fmaf(xsS[t*32+k], W0[(32+k)*32], acc);
    #pragma unroll 8
    for (int k = 0; k < 32; ++k) acc = fmaf(eaS[k], W0[(64+k)*32], acc);
    hS[c] = fmaxf(acc, 0.f);
    __syncthreads();
    float m = pre_b1[c];
    const float* W1 = preW1 + t*1024 + f;
    #pragma unroll 8
    for (int g = 0; g < 32; ++g) m = fmaf(hS[t*32+g], W1[g*32], m);
    sum += m; sq = fmaf(m, m, sq); mn = fminf(mn, m); mx = fmaxf(mx, m);
    __syncthreads();
  }
  const float d = (float)deg;
  const float denom = fmaxf(d, 1.f);
  const float mean = sum / denom;
  const float sd = sqrtf(fmaxf(sq/denom - mean*mean, 0.f) + 1e-5f);
  const float mnz = (deg > 0) ? mn : 0.f;
  const float mxz = (deg > 0) ? mx : 0.f;
  const float logd = logf(denom + 1.f);
  const float s1 = logd / ADL, s2 = ADL / logd;
  aggS[0][c] = sum; aggS[1][c] = mean; aggS[2][c] = mnz; aggS[3][c] = mxz; aggS[4][c] = sd;
  __syncthreads();
  float acc0 = post_b0[c];
  const float* P0 = postW0 + t*16384 + f;
  #pragma unroll 8
  for (int k = 0; k < 32; ++k) acc0 = fmaf(xdS[t*32+k], P0[k*32], acc0);
  float pa0 = 0.f, pa1 = 0.f, pa2 = 0.f;
  for (int a = 0; a < 5; ++a){
    const float* ag = &aggS[a][t*32];
    const float* Pb = P0 + (32 + a*32)*32;
    #pragma unroll 8
    for (int k = 0; k < 32; ++k){
      const float av = ag[k];
      pa0 = fmaf(av, Pb[k*32], pa0);
      pa1 = fmaf(av, Pb[(160+k)*32], pa1);
      pa2 = fmaf(av, Pb[(320+k)*32], pa2);
    }
  }
  hpS[c] = fmaxf(acc0 + pa0 + s1*pa1 + s2*pa2, 0.f);
  __syncthreads();
  float v = post_b1[c];
  const float* PW1 = postW1 + t*1024 + f;
  #pragma unroll 8
  for (int g = 0; g < 32; ++g) v = fmaf(hpS[t*32+g], PW1[g*32], v);
  vS[c] = v;
  __syncthreads();
  float l = b_lin[c];
  #pragma unroll 8
  for (int k = 0; k < 128; ++k) l = fmaf(vS[k], Wlin[k*128 + c], l);
  float ps = l, ps2 = l*l;
  #pragma unroll
  for (int o = 32; o >= 1; o >>= 1){ ps += __shfl_xor(ps, o); ps2 += __shfl_xor(ps2, o); }
  if ((c & 63) == 0){ red[c>>6] = ps; red[2 + (c>>6)] = ps2; }
  __syncthreads();
  const float mu = (red[0] + red[1]) * (1.f/128.f);
  const float var = fmaxf((red[2] + red[3]) * (1.f/128.f) - mu*mu, 0.f);
  const float rstd = rsqrtf(var + 1e-5f);
  out[(size_t)n*128 + c] = xd + fmaxf((l - mu)*rstd*ln_g[c] + ln_b[c], 0.f);
}

// ======================= launch =======================
extern "C" void kernel_launch(void* const* d_in, const int* in_sizes, int n_in,
                              void* d_out, int out_size, void* d_ws, size_t ws_size,
                              hipStream_t stream){
  const float* x       = (const float*)d_in[0];
  const int*   ei      = (const int*)d_in[1];
  const float* eattr   = (const float*)d_in[2];
  const float* Wedge   = (const float*)d_in[3];
  const float* b_edge  = (const float*)d_in[4];
  const float* preW0   = (const float*)d_in[5];
  const float* pre_b0  = (const float*)d_in[6];
  const float* preW1   = (const float*)d_in[7];
  const float* pre_b1  = (const float*)d_in[8];
  const float* postW0  = (const float*)d_in[9];
  const float* post_b0 = (const float*)d_in[10];
  const float* postW1  = (const float*)d_in[11];
  const float* post_b1 = (const float*)d_in[12];
  const float* Wlin    = (const float*)d_in[13];
  const float* b_lin   = (const float*)d_in[14];
  const float* ln_g    = (const float*)d_in[15];
  const float* ln_b    = (const float*)d_in[16];

  char* ws = (char*)d_ws;
  size_t o = 0;
  auto alloc = [&](size_t bytes)->char*{
    char* p = ws + o; o = (o + bytes + 255) & ~((size_t)255); return p;
  };
  int* off    = (int*)alloc((NN + 1) * 4);
  int* cnt    = (int*)alloc(NN * 4);
  int* cursor = (int*)alloc(NN * 4);
  int* eids   = (int*)alloc(NE * 4);
  int* sidc   = (int*)alloc(NE * 4);
  int* bsum   = (int*)alloc(32 * 4);
  u32* preW0H  = (u32*)alloc(6144 * 4);
  u32* preW1H  = (u32*)alloc(2048 * 4);
  float* postW0T = (float*)alloc(65536 * 4);
  float* postW1T = (float*)alloc(4096 * 4);
  float* WlinT   = (float*)alloc(16384 * 4);
  u16* eaH     = (u16*)alloc((size_t)NE * 32 * 2);
  float* agg   = (float*)alloc((size_t)NN * 512 * 4);
  u32* xH      = (u32*)alloc((size_t)NN * 64 * 4);
  const size_t need = o;

  // CSR build (memset replaces k_zero — one less launch)
  hipMemsetAsync(cnt, 0, NN * 4, stream);
  hipMemsetAsync(cursor, 0, NN * 4, stream);
  k_hist<<<(NE + 255)/256, 256, 0, stream>>>(ei, cnt);
  k_scanA<<<30, 1024, 0, stream>>>(cnt, off, bsum);
  k_scanB<<<1, 64, 0, stream>>>(bsum);
  k_scanC<<<(NN + 256)/256, 256, 0, stream>>>(off, bsum);
  k_scatter<<<(NE + 255)/256, 256, 0, stream>>>(ei, off, cursor, eids, sidc);

  if (ws_size < need){
    k_mono<<<NN, 128, 0, stream>>>(x, ei, eattr, Wedge, b_edge,
                                   preW0, pre_b0, preW1, pre_b1,
                                   postW0, post_b0, postW1, post_b1,
                                   Wlin, b_lin, ln_g, ln_b,
                                   off, eids, (float*)d_out);
    return;
  }

  k_prep<<<256, 256, 0, stream>>>(preW0, preW1, postW0, postW1, Wlin,
                                  preW0H, preW1H, postW0T, postW1T, WlinT);
  k_packx<<<(NN*64 + 255)/256, 256, 0, stream>>>(x, xH);
  k_ea<<<(NE + 7)/8, 256, 0, stream>>>(eattr, Wedge, b_edge, eids, eaH);
  k_edge4<<<NN/8, 128, 0, stream>>>(xH, (const u32*)eaH, sidc, preW0H, preW1H,
                                    pre_b0, pre_b1, off, agg);
  k_post<<<NN/12, 128, 0, stream>>>(x, agg, off, postW0T, postW1T, WlinT,
                                    post_b0, post_b1, b_lin, ln_g, ln_b,
                                    (float*)d_out);
}

// Round 16
// 671.740 us; speedup vs baseline: 1.7101x; 1.7101x over previous
//
#include <hip/hip_runtime.h>
#include <hip/hip_bf16.h>

#define NN 30000
#define NE 480000
#define ADL 2.8332133440562162f   // ln(17)

typedef unsigned int u32;
typedef unsigned short u16;

typedef _Float16 half2v __attribute__((ext_vector_type(2)));

__device__ __forceinline__ u16 f2h(float f){
  union { _Float16 h; u16 u; } v; v.h = (_Float16)f; return v.u;
}
__device__ __forceinline__ u32 pack2(float lo, float hi){
  return (u32)f2h(lo) | ((u32)f2h(hi) << 16);
}
__device__ __forceinline__ float dot2f(u32 a, u32 b, float c){
#if defined(__has_builtin) && __has_builtin(__builtin_amdgcn_fdot2)
  union U { u32 u; half2v h; };
  U ua, ub; ua.u = a; ub.u = b;
  return __builtin_amdgcn_fdot2(ua.h, ub.h, c, false);
#else
  float r;
  asm("v_dot2_f32_f16 %0, %1, %2, %3" : "=v"(r) : "v"(a), "v"(b), "v"(c));
  return r;
#endif
}

// ======================= CSR build =======================
__global__ void k_hist(const int* __restrict__ ei, int* __restrict__ cnt){
  int e = blockIdx.x * blockDim.x + threadIdx.x;
  if (e < NE) atomicAdd(&cnt[ei[NE + e]], 1);
}

__global__ __launch_bounds__(1024) void k_scanA(const int* __restrict__ cnt,
                                                int* __restrict__ off, int* __restrict__ bsum){
  __shared__ int buf[1024];
  const int b = blockIdx.x, tid = threadIdx.x;
  const int i = b*1024 + tid;
  int v = (i < NN) ? cnt[i] : 0;
  buf[tid] = v;
  __syncthreads();
  for (int s = 1; s < 1024; s <<= 1){
    int t = (tid >= s) ? buf[tid - s] : 0;
    __syncthreads();
    buf[tid] += t;
    __syncthreads();
  }
  if (i < NN) off[i] = buf[tid] - v;
  if (tid == 1023) bsum[b] = buf[1023];
}

__global__ void k_scanB(int* __restrict__ bsum){
  if (threadIdx.x == 0 && blockIdx.x == 0){
    int acc = 0;
    for (int b = 0; b < 30; ++b){ int v = bsum[b]; bsum[b] = acc; acc += v; }
  }
}

__global__ void k_scanC(int* __restrict__ off, const int* __restrict__ bsum){
  int i = blockIdx.x * blockDim.x + threadIdx.x;
  if (i < NN) off[i] += bsum[i >> 10];
  if (i == NN) off[NN] = NE;
}

__global__ void k_scatter(const int* __restrict__ ei, const int* __restrict__ off,
                          int* __restrict__ cursor, int* __restrict__ eids,
                          int* __restrict__ sidC){
  int e = blockIdx.x * blockDim.x + threadIdx.x;
  if (e < NE){
    int d = ei[NE + e];
    int pos = off[d] + atomicAdd(&cursor[d], 1);
    eids[pos] = e;
    sidC[pos] = ei[e];     // CSR-ordered src ids
  }
}

// ======================= x pre-pack: f32 row -> packed half2 =======================
__global__ void k_packx(const float* __restrict__ x, u32* __restrict__ xH){
  int i = blockIdx.x * blockDim.x + threadIdx.x;
  if (i < NN * 64){
    const float2 v = *(const float2*)(x + (size_t)i * 2);
    xH[i] = pack2(v.x, v.y);
  }
}

// ======================= weight prep =======================
__global__ void k_prep(const float* __restrict__ preW0, const float* __restrict__ preW1,
                       const float* __restrict__ postW0, const float* __restrict__ postW1,
                       const float* __restrict__ Wlin,
                       u32* __restrict__ preW0H, u32* __restrict__ preW1H,
                       float* __restrict__ postW0T, float* __restrict__ postW1T,
                       float* __restrict__ WlinT)
{
  int i = blockIdx.x * blockDim.x + threadIdx.x;
  if (i < 65536){ int c = i >> 9, kk = i & 511;
    postW0T[i] = postW0[(c >> 5)*16384 + kk*32 + (c & 31)]; }
  if (i < 6144){          // preW0H[c][q]: pair (k=2q, k=2q+1) of preW0[t][k][f]
    int c = i / 48, q = i % 48;
    int t = c >> 5, f = c & 31;
    preW0H[i] = pack2(preW0[t*3072 + (2*q)*32 + f], preW0[t*3072 + (2*q+1)*32 + f]);
  }
  if (i < 2048){          // preW1H[c][q]: pair (g=2q, g=2q+1) of preW1[t][g][f]
    int c = i / 16, q = i % 16;
    int t = c >> 5, f = c & 31;
    preW1H[i] = pack2(preW1[t*1024 + (2*q)*32 + f], preW1[t*1024 + (2*q+1)*32 + f]);
  }
  if (i < 4096){ int c = i >> 5, g = i & 31;
    postW1T[i] = postW1[(c >> 5)*1024 + g*32 + (c & 31)]; }
  if (i < 16384){ int c = i >> 7, k = i & 127; WlinT[i] = Wlin[k*128 + c]; }
}

// ======================= ea precompute, CSR-ordered, f16 output =======================
__global__ __launch_bounds__(256) void k_ea(const float* __restrict__ eattr,
                                            const float* __restrict__ Wedge,
                                            const float* __restrict__ b_edge,
                                            const int* __restrict__ eids,
                                            u16* __restrict__ eaH)
{
  __shared__ float WS[512];
  __shared__ float bS[32];
  const int tid = threadIdx.x;
  WS[tid]       = Wedge[tid];
  WS[tid + 256] = Wedge[tid + 256];
  if (tid < 32) bS[tid] = b_edge[tid];
  __syncthreads();
  const int g = tid & 31;
  const int pos = blockIdx.x * 8 + (tid >> 5);
  if (pos < NE){
    const int e = eids[pos];
    const float* ar = eattr + (size_t)e * 16;
    float acc = bS[g];
    #pragma unroll
    for (int ii = 0; ii < 16; ++ii) acc = fmaf(ar[ii], WS[ii*32 + g], acc);
    eaH[(size_t)pos*32 + g] = f2h(acc);
  }
}

// ======================= edge phase v8: whole-window staging (16 edges), max MLP =======================
// R14 held 2 gathers/thread in flight; latency-bound at VALU 46%. Here: stage a FULL 16-edge
// window in one burst (8 xH gathers + 2 ea loads per thread, all independent), one barrier,
// then 16 edges of compute with no inner barriers (hP is wave-local). a0n computed between
// load-issue and drain. Reverted to proven __launch_bounds__(128,2) (R15's (128,4) spilled).
__global__ __launch_bounds__(128, 2) void k_edge6(
  const u32* __restrict__ xHu,
  const u32* __restrict__ eaHu,
  const int* __restrict__ sidC,
  const u32* __restrict__ preW0H, const u32* __restrict__ preW1H,
  const float* __restrict__ pre_b0, const float* __restrict__ pre_b1,
  const int* __restrict__ off,
  float* __restrict__ agg)
{
  const int c = threadIdx.x;        // channel 0..127
  const int t = c >> 5;             // tower

  __shared__ __align__(16) u32 xdH[64];        // dst-x packed pairs
  __shared__ __align__(16) u32 xsA[16][64];    // whole window of src rows
  __shared__ __align__(16) u32 eaA[16][16];    // whole window of ea rows
  __shared__ __align__(16) u32 hP[4][64];      // wave-local h (u32 both ways)
  __shared__ int sidS[16];

  u32 w0p[48], w1p[16];
  #pragma unroll
  for (int q = 0; q < 12; ++q) *(uint4*)&w0p[q*4] = *(const uint4*)(preW0H + (size_t)c*48 + q*4);
  #pragma unroll
  for (int q = 0; q < 4; ++q)  *(uint4*)&w1p[q*4] = *(const uint4*)(preW1H + (size_t)c*16 + q*4);
  const float pb0 = pre_b0[c];
  const float pb1 = pre_b1[c];

  for (int nn = 0; nn < 8; ++nn){
    const int n = blockIdx.x * 8 + nn;
    __syncthreads();                 // prior node's buffers fully consumed
    if (c < 64) xdH[c] = xHu[(size_t)n*64 + c];
    const int e0 = off[n], e1 = off[n+1];
    float sum = 0.f, sq = 0.f;
    float mn = __builtin_inff(), mx = -__builtin_inff();

    for (int base = e0; base < e1; base += 16){
      const int nv = min(16, e1 - base);
      if (c < nv) sidS[c] = sidC[base + c];
      __syncthreads();               // sidS visible; prior window compute done

      // burst-stage the whole window: 8 independent xH gathers per thread
      #pragma unroll
      for (int k = 0; k < 8; ++k){
        const int idx = k*128 + c;
        const int row = idx >> 6, col = idx & 63;
        const int r = min(row, nv-1);
        xsA[row][col] = xHu[(size_t)sidS[r]*64 + col];
      }
      // ea: 256 words, 2 per thread
      #pragma unroll
      for (int k = 0; k < 2; ++k){
        const int idx = k*128 + c;
        const int row = idx >> 4, q = idx & 15;
        const int r = min(row, nv-1);
        eaA[row][q] = eaHu[(size_t)(base + r)*16 + q];
      }

      // dst-slice dot (covers part of the gather latency before the drain)
      float a0n = pb0;
      #pragma unroll
      for (int i4 = 0; i4 < 4; ++i4){
        const uint4 xv = *(const uint4*)&xdH[t*16 + i4*4];
        a0n = dot2f(xv.x, w0p[i4*4+0], a0n);
        a0n = dot2f(xv.y, w0p[i4*4+1], a0n);
        a0n = dot2f(xv.z, w0p[i4*4+2], a0n);
        a0n = dot2f(xv.w, w0p[i4*4+3], a0n);
      }
      __syncthreads();               // staged window visible

      // compute 16 edges in 4 sub-batches of 4; no barriers (hP wave-local, xsA read-only)
      for (int sb = 0; sb*4 < nv; ++sb){
        float aXs[4] = {0,0,0,0}, aEa[4] = {0,0,0,0};
        #pragma unroll
        for (int i4 = 0; i4 < 4; ++i4){
          uint4 xsv[4], eav[4];
          #pragma unroll
          for (int e = 0; e < 4; ++e){
            xsv[e] = *(const uint4*)&xsA[sb*4 + e][t*16 + i4*4];
            eav[e] = *(const uint4*)&eaA[sb*4 + e][i4*4];
          }
          const u32 wx0 = w0p[16+i4*4+0], wx1 = w0p[16+i4*4+1];
          const u32 wx2 = w0p[16+i4*4+2], wx3 = w0p[16+i4*4+3];
          const u32 we0 = w0p[32+i4*4+0], we1 = w0p[32+i4*4+1];
          const u32 we2 = w0p[32+i4*4+2], we3 = w0p[32+i4*4+3];
          #pragma unroll
          for (int e = 0; e < 4; ++e){
            aXs[e] = dot2f(xsv[e].x, wx0, aXs[e]);
            aXs[e] = dot2f(xsv[e].y, wx1, aXs[e]);
            aXs[e] = dot2f(xsv[e].z, wx2, aXs[e]);
            aXs[e] = dot2f(xsv[e].w, wx3, aXs[e]);
            aEa[e] = dot2f(eav[e].x, we0, aEa[e]);
            aEa[e] = dot2f(eav[e].y, we1, aEa[e]);
            aEa[e] = dot2f(eav[e].z, we2, aEa[e]);
            aEa[e] = dot2f(eav[e].w, we3, aEa[e]);
          }
        }
        // pack h pairwise (u32-typed store; even lanes write word (c, c+1))
        #pragma unroll
        for (int e = 0; e < 4; ++e){
          const float h = fmaxf(a0n + aXs[e] + aEa[e], 0.f);
          const u32 mine = (u32)f2h(h);
          const u32 oth  = (u32)__shfl_xor((int)mine, 1);
          if ((c & 1) == 0) hP[e][c >> 1] = mine | (oth << 16);
        }
        // layer1 (b128 hP loads; within-wave)
        float mm[4] = {pb1, pb1, pb1, pb1};
        #pragma unroll
        for (int i4 = 0; i4 < 4; ++i4){
          uint4 hv[4];
          #pragma unroll
          for (int e = 0; e < 4; ++e) hv[e] = *(const uint4*)&hP[e][t*16 + i4*4];
          const u32 w0v = w1p[i4*4+0], w1v = w1p[i4*4+1];
          const u32 w2v = w1p[i4*4+2], w3v = w1p[i4*4+3];
          #pragma unroll
          for (int e = 0; e < 4; ++e){
            mm[e] = dot2f(hv[e].x, w0v, mm[e]);
            mm[e] = dot2f(hv[e].y, w1v, mm[e]);
            mm[e] = dot2f(hv[e].z, w2v, mm[e]);
            mm[e] = dot2f(hv[e].w, w3v, mm[e]);
          }
        }
        #pragma unroll
        for (int e = 0; e < 4; ++e){
          if (sb*4 + e < nv){
            sum += mm[e]; sq = fmaf(mm[e], mm[e], sq);
            mn = fminf(mn, mm[e]); mx = fmaxf(mx, mm[e]);
          }
        }
      }
    }

    const int deg = e1 - e0;
    const size_t b = (size_t)n * 512;
    agg[b + c]       = sum;
    agg[b + 128 + c] = sq;
    agg[b + 256 + c] = (deg > 0) ? mn : 0.f;
    agg[b + 384 + c] = (deg > 0) ? mx : 0.f;
  }
}

// ======================= node phase: G=12 nodes/block, register-tiled =======================
__global__ __launch_bounds__(128, 2) void k_post(
  const float* __restrict__ x, const float* __restrict__ agg,
  const int* __restrict__ off,
  const float* __restrict__ postW0T, const float* __restrict__ postW1T,
  const float* __restrict__ WlinT,
  const float* __restrict__ post_b0, const float* __restrict__ post_b1,
  const float* __restrict__ b_lin, const float* __restrict__ ln_g,
  const float* __restrict__ ln_b,
  float* __restrict__ out)
{
  const int c = threadIdx.x;
  const int t = c >> 5;
  const int n0 = blockIdx.x * 12;

  __shared__ __align__(16) float aS[12][768];
  __shared__ __align__(16) float hpS[12][128];
  __shared__ __align__(16) float vS[12][128];
  __shared__ float s1S[12], s2S[12], muS[12], rsS[12];

  #pragma unroll
  for (int n = 0; n < 12; ++n){
    const size_t nb = (size_t)(n0 + n);
    aS[n][c] = x[nb*128 + c];
    float sum = agg[nb*512 + c];
    float sq  = agg[nb*512 + 128 + c];
    float mnv = agg[nb*512 + 256 + c];
    float mxv = agg[nb*512 + 384 + c];
    int deg = off[n0+n+1] - off[n0+n];
    float denom = fmaxf((float)deg, 1.f);
    float mean = sum / denom;
    float sd = sqrtf(fmaxf(sq/denom - mean*mean, 0.f) + 1e-5f);
    aS[n][128 + c] = sum;  aS[n][256 + c] = mean;
    aS[n][384 + c] = mnv;  aS[n][512 + c] = mxv;  aS[n][640 + c] = sd;
  }
  if (c < 12){
    int deg = off[n0+c+1] - off[n0+c];
    float logd = logf(fmaxf((float)deg, 1.f) + 1.f);
    s1S[c] = logd / ADL; s2S[c] = ADL / logd;
  }
  __syncthreads();

  float acc[12], pa1[12], pa2[12];
  const float pb0 = post_b0[c];
  #pragma unroll
  for (int n = 0; n < 12; ++n){ acc[n] = pb0; pa1[n] = 0.f; pa2[n] = 0.f; }
  const float* Wp = postW0T + (size_t)c * 512;
  #pragma unroll
  for (int k4 = 0; k4 < 8; ++k4){
    float4 w = *(const float4*)(Wp + k4*4);
    #pragma unroll
    for (int n = 0; n < 12; ++n){
      float4 a = *(const float4*)&aS[n][t*32 + k4*4];
      acc[n] = fmaf(a.x, w.x, acc[n]); acc[n] = fmaf(a.y, w.y, acc[n]);
      acc[n] = fmaf(a.z, w.z, acc[n]); acc[n] = fmaf(a.w, w.w, acc[n]);
    }
  }
  for (int a = 0; a < 5; ++a){
    #pragma unroll
    for (int k4 = 0; k4 < 8; ++k4){
      float4 w0v = *(const float4*)(Wp + 32  + a*32 + k4*4);
      float4 w1v = *(const float4*)(Wp + 192 + a*32 + k4*4);
      float4 w2v = *(const float4*)(Wp + 352 + a*32 + k4*4);
      #pragma unroll
      for (int n = 0; n < 12; ++n){
        float4 av = *(const float4*)&aS[n][128 + a*128 + t*32 + k4*4];
        acc[n] = fmaf(av.x, w0v.x, acc[n]); acc[n] = fmaf(av.y, w0v.y, acc[n]);
        acc[n] = fmaf(av.z, w0v.z, acc[n]); acc[n] = fmaf(av.w, w0v.w, acc[n]);
        pa1[n] = fmaf(av.x, w1v.x, pa1[n]); pa1[n] = fmaf(av.y, w1v.y, pa1[n]);
        pa1[n] = fmaf(av.z, w1v.z, pa1[n]); pa1[n] = fmaf(av.w, w1v.w, pa1[n]);
        pa2[n] = fmaf(av.x, w2v.x, pa2[n]); pa2[n] = fmaf(av.y, w2v.y, pa2[n]);
        pa2[n] = fmaf(av.z, w2v.z, pa2[n]); pa2[n] = fmaf(av.w, w2v.w, pa2[n]);
      }
    }
  }
  #pragma unroll
  for (int n = 0; n < 12; ++n)
    hpS[n][c] = fmaxf(acc[n] + s1S[n]*pa1[n] + s2S[n]*pa2[n], 0.f);
  __syncthreads();

  float w1r[32];
  #pragma unroll
  for (int q = 0; q < 8; ++q) *(float4*)&w1r[q*4] = *(const float4*)(postW1T + (size_t)c*32 + q*4);
  float a2[12];
  const float pb1v = post_b1[c];
  #pragma unroll
  for (int n = 0; n < 12; ++n) a2[n] = pb1v;
  #pragma unroll
  for (int g4 = 0; g4 < 8; ++g4){
    #pragma unroll
    for (int n = 0; n < 12; ++n){
      float4 h = *(const float4*)&hpS[n][t*32 + g4*4];
      a2[n] = fmaf(h.x, w1r[g4*4+0], a2[n]); a2[n] = fmaf(h.y, w1r[g4*4+1], a2[n]);
      a2[n] = fmaf(h.z, w1r[g4*4+2], a2[n]); a2[n] = fmaf(h.w, w1r[g4*4+3], a2[n]);
    }
  }
  #pragma unroll
  for (int n = 0; n < 12; ++n) vS[n][c] = a2[n];
  __syncthreads();

  float a3[12];
  const float blv = b_lin[c];
  #pragma unroll
  for (int n = 0; n < 12; ++n) a3[n] = blv;
  const float* Wl = WlinT + (size_t)c * 128;
  #pragma unroll 8
  for (int k4 = 0; k4 < 32; ++k4){
    float4 w = *(const float4*)(Wl + k4*4);
    #pragma unroll
    for (int n = 0; n < 12; ++n){
      float4 v = *(const float4*)&vS[n][k4*4];
      a3[n] = fmaf(v.x, w.x, a3[n]); a3[n] = fmaf(v.y, w.y, a3[n]);
      a3[n] = fmaf(v.z, w.z, a3[n]); a3[n] = fmaf(v.w, w.w, a3[n]);
    }
  }

  #pragma unroll
  for (int n = 0; n < 12; ++n) hpS[n][c] = a3[n];
  __syncthreads();
  {
    const int n = c >> 3, seg = c & 7;
    if (n < 12){
      float ps = 0.f, ps2 = 0.f;
      #pragma unroll
      for (int k = 0; k < 16; ++k){
        float v = hpS[n][seg*16 + k];
        ps += v; ps2 = fmaf(v, v, ps2);
      }
      ps += __shfl_xor(ps, 1); ps2 += __shfl_xor(ps2, 1);
      ps += __shfl_xor(ps, 2); ps2 += __shfl_xor(ps2, 2);
      ps += __shfl_xor(ps, 4); ps2 += __shfl_xor(ps2, 4);
      if (seg == 0){
        float mu = ps * (1.f/128.f);
        float var = fmaxf(ps2 * (1.f/128.f) - mu*mu, 0.f);
        muS[n] = mu; rsS[n] = rsqrtf(var + 1e-5f);
      }
    }
  }
  __syncthreads();
  const float gv = ln_g[c], bv = ln_b[c];
  #pragma unroll
  for (int n = 0; n < 12; ++n){
    float o = aS[n][c] + fmaxf((a3[n] - muS[n])*rsS[n]*gv + bv, 0.f);
    out[(size_t)(n0 + n)*128 + c] = o;
  }
}

// ======================= fallback: proven monolithic kernel (R3, f32) =======================
__global__ __launch_bounds__(128) void k_mono(
  const float* __restrict__ x, const int* __restrict__ ei,
  const float* __restrict__ eattr,
  const float* __restrict__ Wedge, const float* __restrict__ b_edge,
  const float* __restrict__ preW0, const float* __restrict__ pre_b0,
  const float* __restrict__ preW1, const float* __restrict__ pre_b1,
  const float* __restrict__ postW0, const float* __restrict__ post_b0,
  const float* __restrict__ postW1, const float* __restrict__ post_b1,
  const float* __restrict__ Wlin, const float* __restrict__ b_lin,
  const float* __restrict__ ln_g, const float* __restrict__ ln_b,
  const int* __restrict__ off, const int* __restrict__ eids,
  float* __restrict__ out)
{
  const int n = blockIdx.x;
  const int c = threadIdx.x;
  const int t = c >> 5, f = c & 31;
  __shared__ float xdS[128], xsS[128], eaS[32], hS[128];
  __shared__ float aggS[5][128], hpS[128], vS[128], red[4];

  const float xd = x[(size_t)n*128 + c];
  xdS[c] = xd;
  const int e0 = off[n], e1 = off[n+1];
  const int deg = e1 - e0;
  float sum = 0.f, sq = 0.f, mn = __builtin_inff(), mx = -__builtin_inff();
  __syncthreads();

  for (int idx = e0; idx < e1; ++idx){
    const int e = eids[idx];
    const int s = ei[e];
    xsS[c] = x[(size_t)s*128 + c];
    if (c < 32){
      float acc = b_edge[c];
      #pragma unroll
      for (int ii = 0; ii < 16; ++ii) acc = fmaf(eattr[(size_t)e*16 + ii], Wedge[ii*32 + c], acc);
      eaS[c] = acc;
    }
    __syncthreads();
    float acc = pre_b0[c];
    const float* W0 = preW0 + t*3072 + f;
    #pragma unroll 8
    for (int k = 0; k < 32; ++k) acc = fmaf(xdS[t*32+k], W0[k*32], acc);
    #pragma unroll 8
    for (int k = 0; k < 32; ++k) acc = fmaf(xsS[t*32+k], W0[(32+k)*32], acc);
    #pragma unroll 8
    for (int k = 0; k < 32; ++k) acc = fmaf(eaS[k], W0[(64+k)*32], acc);
    hS[c] = fmaxf(acc, 0.f);
    __syncthreads();
    float m = pre_b1[c];
    const float* W1 = preW1 + t*1024 + f;
    #pragma unroll 8
    for (int g = 0; g < 32; ++g) m = fmaf(hS[t*32+g], W1[g*32], m);
    sum += m; sq = fmaf(m, m, sq); mn = fminf(mn, m); mx = fmaxf(mx, m);
    __syncthreads();
  }
  const float d = (float)deg;
  const float denom = fmaxf(d, 1.f);
  const float mean = sum / denom;
  const float sd = sqrtf(fmaxf(sq/denom - mean*mean, 0.f) + 1e-5f);
  const float mnz = (deg > 0) ? mn : 0.f;
  const float mxz = (deg > 0) ? mx : 0.f;
  const float logd = logf(denom + 1.f);
  const float s1 = logd / ADL, s2 = ADL / logd;
  aggS[0][c] = sum; aggS[1][c] = mean; aggS[2][c] = mnz; aggS[3][c] = mxz; aggS[4][c] = sd;
  __syncthreads();
  float acc0 = post_b0[c];
  const float* P0 = postW0 + t*16384 + f;
  #pragma unroll 8
  for (int k = 0; k < 32; ++k) acc0 = fmaf(xdS[t*32+k], P0[k*32], acc0);
  float pa0 = 0.f, pa1 = 0.f, pa2 = 0.f;
  for (int a = 0; a < 5; ++a){
    const float* ag = &aggS[a][t*32];
    const float* Pb = P0 + (32 + a*32)*32;
    #pragma unroll 8
    for (int k = 0; k < 32; ++k){
      const float av = ag[k];
      pa0 = fmaf(av, Pb[k*32], pa0);
      pa1 = fmaf(av, Pb[(160+k)*32], pa1);
      pa2 = fmaf(av, Pb[(320+k)*32], pa2);
    }
  }
  hpS[c] = fmaxf(acc0 + pa0 + s1*pa1 + s2*pa2, 0.f);
  __syncthreads();
  float v = post_b1[c];
  const float* PW1 = postW1 + t*1024 + f;
  #pragma unroll 8
  for (int g = 0; g < 32; ++g) v = fmaf(hpS[t*32+g], PW1[g*32], v);
  vS[c] = v;
  __syncthreads();
  float l = b_lin[c];
  #pragma unroll 8
  for (int k = 0; k < 128; ++k) l = fmaf(vS[k], Wlin[k*128 + c], l);
  float ps = l, ps2 = l*l;
  #pragma unroll
  for (int o = 32; o >= 1; o >>= 1){ ps += __shfl_xor(ps, o); ps2 += __shfl_xor(ps2, o); }
  if ((c & 63) == 0){ red[c>>6] = ps; red[2 + (c>>6)] = ps2; }
  __syncthreads();
  const float mu = (red[0] + red[1]) * (1.f/128.f);
  const float var = fmaxf((red[2] + red[3]) * (1.f/128.f) - mu*mu, 0.f);
  const float rstd = rsqrtf(var + 1e-5f);
  out[(size_t)n*128 + c] = xd + fmaxf((l - mu)*rstd*ln_g[c] + ln_b[c], 0.f);
}

// ======================= launch =======================
extern "C" void kernel_launch(void* const* d_in, const int* in_sizes, int n_in,
                              void* d_out, int out_size, void* d_ws, size_t ws_size,
                              hipStream_t stream){
  const float* x       = (const float*)d_in[0];
  const int*   ei      = (const int*)d_in[1];
  const float* eattr   = (const float*)d_in[2];
  const float* Wedge   = (const float*)d_in[3];
  const float* b_edge  = (const float*)d_in[4];
  const float* preW0   = (const float*)d_in[5];
  const float* pre_b0  = (const float*)d_in[6];
  const float* preW1   = (const float*)d_in[7];
  const float* pre_b1  = (const float*)d_in[8];
  const float* postW0  = (const float*)d_in[9];
  const float* post_b0 = (const float*)d_in[10];
  const float* postW1  = (const float*)d_in[11];
  const float* post_b1 = (const float*)d_in[12];
  const float* Wlin    = (const float*)d_in[13];
  const float* b_lin   = (const float*)d_in[14];
  const float* ln_g    = (const float*)d_in[15];
  const float* ln_b    = (const float*)d_in[16];

  char* ws = (char*)d_ws;
  size_t o = 0;
  auto alloc = [&](size_t bytes)->char*{
    char* p = ws + o; o = (o + bytes + 255) & ~((size_t)255); return p;
  };
  int* off    = (int*)alloc((NN + 1) * 4);
  int* cnt    = (int*)alloc(NN * 4);
  int* cursor = (int*)alloc(NN * 4);
  int* eids   = (int*)alloc(NE * 4);
  int* sidc   = (int*)alloc(NE * 4);
  int* bsum   = (int*)alloc(32 * 4);
  u32* preW0H  = (u32*)alloc(6144 * 4);
  u32* preW1H  = (u32*)alloc(2048 * 4);
  float* postW0T = (float*)alloc(65536 * 4);
  float* postW1T = (float*)alloc(4096 * 4);
  float* WlinT   = (float*)alloc(16384 * 4);
  u16* eaH     = (u16*)alloc((size_t)NE * 32 * 2);
  float* agg   = (float*)alloc((size_t)NN * 512 * 4);
  u32* xH      = (u32*)alloc((size_t)NN * 64 * 4);
  const size_t need = o;

  // CSR build
  hipMemsetAsync(cnt, 0, NN * 4, stream);
  hipMemsetAsync(cursor, 0, NN * 4, stream);
  k_hist<<<(NE + 255)/256, 256, 0, stream>>>(ei, cnt);
  k_scanA<<<30, 1024, 0, stream>>>(cnt, off, bsum);
  k_scanB<<<1, 64, 0, stream>>>(bsum);
  k_scanC<<<(NN + 256)/256, 256, 0, stream>>>(off, bsum);
  k_scatter<<<(NE + 255)/256, 256, 0, stream>>>(ei, off, cursor, eids, sidc);

  if (ws_size < need){
    k_mono<<<NN, 128, 0, stream>>>(x, ei, eattr, Wedge, b_edge,
                                   preW0, pre_b0, preW1, pre_b1,
                                   postW0, post_b0, postW1, post_b1,
                                   Wlin, b_lin, ln_g, ln_b,
                                   off, eids, (float*)d_out);
    return;
  }

  k_prep<<<256, 256, 0, stream>>>(preW0, preW1, postW0, postW1, Wlin,
                                  preW0H, preW1H, postW0T, postW1T, WlinT);
  k_packx<<<(NN*64 + 255)/256, 256, 0, stream>>>(x, xH);
  k_ea<<<(NE + 7)/8, 256, 0, stream>>>(eattr, Wedge, b_edge, eids, eaH);
  k_edge6<<<NN/8, 128, 0, stream>>>(xH, (const u32*)eaH, sidc, preW0H, preW1H,
                                    pre_b0, pre_b1, off, agg);
  k_post<<<NN/12, 128, 0, stream>>>(x, agg, off, postW0T, postW1T, WlinT,
                                    post_b0, post_b1, b_lin, ln_g, ln_b,
                                    (float*)d_out);
}

// Round 17
// 475.717 us; speedup vs baseline: 2.4147x; 1.4121x over previous
//
#include <hip/hip_runtime.h>
#include <hip/hip_bf16.h>

#define NN 30000
#define NE 480000
#define ADL 2.8332133440562162f   // ln(17)

typedef unsigned int u32;
typedef unsigned short u16;

typedef _Float16 half2v __attribute__((ext_vector_type(2)));

__device__ __forceinline__ u16 f2h(float f){
  union { _Float16 h; u16 u; } v; v.h = (_Float16)f; return v.u;
}
__device__ __forceinline__ u32 pack2(float lo, float hi){
  return (u32)f2h(lo) | ((u32)f2h(hi) << 16);
}
__device__ __forceinline__ float dot2f(u32 a, u32 b, float c){
#if defined(__has_builtin) && __has_builtin(__builtin_amdgcn_fdot2)
  union U { u32 u; half2v h; };
  U ua, ub; ua.u = a; ub.u = b;
  return __builtin_amdgcn_fdot2(ua.h, ub.h, c, false);
#else
  float r;
  asm("v_dot2_f32_f16 %0, %1, %2, %3" : "=v"(r) : "v"(a), "v"(b), "v"(c));
  return r;
#endif
}

// ======================= CSR build =======================
__global__ void k_hist(const int* __restrict__ ei, int* __restrict__ cnt){
  int e = blockIdx.x * blockDim.x + threadIdx.x;
  if (e < NE) atomicAdd(&cnt[ei[NE + e]], 1);
}

__global__ __launch_bounds__(1024) void k_scanA(const int* __restrict__ cnt,
                                                int* __restrict__ off, int* __restrict__ bsum){
  __shared__ int buf[1024];
  const int b = blockIdx.x, tid = threadIdx.x;
  const int i = b*1024 + tid;
  int v = (i < NN) ? cnt[i] : 0;
  buf[tid] = v;
  __syncthreads();
  for (int s = 1; s < 1024; s <<= 1){
    int t = (tid >= s) ? buf[tid - s] : 0;
    __syncthreads();
    buf[tid] += t;
    __syncthreads();
  }
  if (i < NN) off[i] = buf[tid] - v;
  if (tid == 1023) bsum[b] = buf[1023];
}

// scanB inlined: each thread accumulates its 30-entry bsum prefix (L2-resident, trivial)
__global__ void k_scanC(int* __restrict__ off, const int* __restrict__ bsum){
  int i = blockIdx.x * blockDim.x + threadIdx.x;
  if (i < NN){
    int pre = 0;
    const int nb = i >> 10;
    for (int b = 0; b < nb; ++b) pre += bsum[b];
    off[i] += pre;
  }
  if (i == NN) off[NN] = NE;
}

// scatter: builds eids (fallback), sidC (CSR src ids), eattrH (CSR-ordered f16-packed edge attrs)
__global__ void k_scatter(const int* __restrict__ ei, const float* __restrict__ eattr,
                          const int* __restrict__ off,
                          int* __restrict__ cursor, int* __restrict__ eids,
                          int* __restrict__ sidC, u32* __restrict__ eattrH){
  int e = blockIdx.x * blockDim.x + threadIdx.x;
  if (e < NE){
    int d = ei[NE + e];
    int pos = off[d] + atomicAdd(&cursor[d], 1);
    eids[pos] = e;
    sidC[pos] = ei[e];
    const float* ar = eattr + (size_t)e * 16;
    u32* dst = eattrH + (size_t)pos * 8;
    #pragma unroll
    for (int q = 0; q < 8; ++q) dst[q] = pack2(ar[2*q], ar[2*q+1]);
  }
}

// ======================= prep: weight transposes + x pre-pack + composed ea matrix =======================
__global__ void k_prep(const float* __restrict__ x,
                       const float* __restrict__ preW0, const float* __restrict__ preW1,
                       const float* __restrict__ postW0, const float* __restrict__ postW1,
                       const float* __restrict__ Wlin,
                       const float* __restrict__ Wedge, const float* __restrict__ b_edge,
                       const float* __restrict__ pre_b0,
                       u32* __restrict__ preW0H, u32* __restrict__ preW1H,
                       float* __restrict__ postW0T, float* __restrict__ postW1T,
                       float* __restrict__ WlinT,
                       u16* __restrict__ eaM16, float* __restrict__ pre_b0F,
                       u32* __restrict__ xH)
{
  int i = blockIdx.x * blockDim.x + threadIdx.x;
  if (i < NN * 64){                       // x pre-pack (f32 -> half2)
    const float2 v = *(const float2*)(x + (size_t)i * 2);
    xH[i] = pack2(v.x, v.y);
  }
  if (i < 65536){ int c = i >> 9, kk = i & 511;
    postW0T[i] = postW0[(c >> 5)*16384 + kk*32 + (c & 31)]; }
  if (i < 4096){                          // preW0H[c][q]: xd+xs pairs only (k=0..63)
    int c = i >> 5, q = i & 31;
    int t = c >> 5, f = c & 31;
    preW0H[i] = pack2(preW0[t*3072 + (2*q)*32 + f], preW0[t*3072 + (2*q+1)*32 + f]);
  }
  if (i < 2048){                          // preW1H[c][q]
    int c = i / 16, q = i % 16;
    int t = c >> 5, f = c & 31;
    preW1H[i] = pack2(preW1[t*1024 + (2*q)*32 + f], preW1[t*1024 + (2*q+1)*32 + f]);
  }
  if (i < 2048){                          // composed M[kk][c] = sum_g Wedge[kk][g]*W0ea[t][g][f]
    int c = i >> 4, kk = i & 15;
    int t = c >> 5, f = c & 31;
    float acc = 0.f;
    #pragma unroll 8
    for (int g = 0; g < 32; ++g)
      acc = fmaf(Wedge[kk*32 + g], preW0[t*3072 + (64+g)*32 + f], acc);
    eaM16[c*16 + kk] = f2h(acc);
  }
  if (i < 128){                           // pre_b0F[c] = pre_b0[c] + b_edge . W0ea[:,c]
    int t = i >> 5, f = i & 31;
    float acc = pre_b0[i];
    #pragma unroll 8
    for (int g = 0; g < 32; ++g)
      acc = fmaf(b_edge[g], preW0[t*3072 + (64+g)*32 + f], acc);
    pre_b0F[i] = acc;
  }
  if (i < 4096){ int c = i >> 5, g = i & 31;
    postW1T[i] = postW1[(c >> 5)*1024 + g*32 + (c & 31)]; }
  if (i < 16384){ int c = i >> 7, k = i & 127; WlinT[i] = Wlin[k*128 + c]; }
}

// ======================= edge phase (R14-proven pipeline; ea path composed through layer0) =======================
// Structure byte-identical to R14's 265us k_edge4 except the ea stream: eaH (16 u32/edge)
// replaced by composed eattrH (8 u32/edge) dotted with eaM (8 u32 regs). FETCH 64->~49MB,
// 16->8 ea dot2s, fewer regs. __launch_bounds__(128,2) (R15's (128,4) spilled).
__global__ __launch_bounds__(128, 2) void k_edge4(
  const u32* __restrict__ xHu,
  const u32* __restrict__ atHu,
  const int* __restrict__ sidC,
  const u32* __restrict__ preW0H, const u32* __restrict__ preW1H,
  const u32* __restrict__ eaMu,
  const float* __restrict__ pre_b0F, const float* __restrict__ pre_b1,
  const int* __restrict__ off,
  float* __restrict__ agg)
{
  const int c = threadIdx.x;        // channel 0..127
  const int t = c >> 5;             // tower

  __shared__ __align__(16) u32 xdH[64];           // dst-x packed pairs
  __shared__ __align__(16) u32 xsH[2][4][64];     // [buf][edge-in-group][pair]
  __shared__ __align__(16) u32 atS[2][4][8];      // [buf][edge][eattr half2 pair]
  __shared__ __align__(16) u32 hP[4][64];         // wave-local h (u32 both ways)
  __shared__ int sidS[64];

  u32 w0p[32], w1p[16], wea[8];
  #pragma unroll
  for (int q = 0; q < 8; ++q) *(uint4*)&w0p[q*4] = *(const uint4*)(preW0H + (size_t)c*32 + q*4);
  #pragma unroll
  for (int q = 0; q < 4; ++q) *(uint4*)&w1p[q*4] = *(const uint4*)(preW1H + (size_t)c*16 + q*4);
  #pragma unroll
  for (int q = 0; q < 2; ++q) *(uint4*)&wea[q*4] = *(const uint4*)(eaMu + (size_t)c*8 + q*4);
  const float pb0 = pre_b0F[c];
  const float pb1 = pre_b1[c];

  const int el = c >> 6;            // this thread stages edges el and el+2
  const int eh = el + 2;
  const int col = c & 63;

  for (int nn = 0; nn < 8; ++nn){
    const int n = blockIdx.x * 8 + nn;
    __syncthreads();                 // protect xdH + buffers from previous node
    if (c < 64) xdH[c] = xHu[(size_t)n*64 + c];
    const int e0 = off[n], e1 = off[n+1];
    float sum = 0.f, sq = 0.f;
    float mn = __builtin_inff(), mx = -__builtin_inff();

    for (int base = e0; base < e1; base += 64){
      const int nv = min(64, e1 - base);
      if (c < nv) sidS[c] = sidC[base + c];
      __syncthreads();               // sidS + xdH visible

      // dst-slice dot: identical for every edge of this node — once per window
      float a0n = pb0;
      #pragma unroll
      for (int i4 = 0; i4 < 4; ++i4){
        const uint4 xv = *(const uint4*)&xdH[t*16 + i4*4];
        a0n = dot2f(xv.x, w0p[i4*4+0], a0n);
        a0n = dot2f(xv.y, w0p[i4*4+1], a0n);
        a0n = dot2f(xv.z, w0p[i4*4+2], a0n);
        a0n = dot2f(xv.w, w0p[i4*4+3], a0n);
      }

      const int np = (nv + 3) >> 2;

      // prologue: stage group 0 into buf 0
      {
        const int g0 = min(el, nv-1), g1 = min(eh, nv-1);
        xsH[0][el][col] = xHu[(size_t)sidS[g0]*64 + col];
        xsH[0][eh][col] = xHu[(size_t)sidS[g1]*64 + col];
        if (c < 32){
          const int e = c >> 3, q = c & 7;
          atS[0][e][q] = atHu[(size_t)(base + min(e, nv-1))*8 + q];
        }
      }
      __syncthreads();

      for (int p = 0; p < np; ++p){
        const int buf = p & 1;
        const int sub = p * 4;
        const bool hasNext = (p + 1 < np);     // block-uniform branch

        // issue next-group global loads into registers (latency hides under compute)
        u32 nxs0 = 0, nxs1 = 0, nat = 0;
        if (hasNext){
          const int s2 = sub + 4;
          const int g0 = min(s2 + el, nv-1), g1 = min(s2 + eh, nv-1);
          nxs0 = xHu[(size_t)sidS[g0]*64 + col];
          nxs1 = xHu[(size_t)sidS[g1]*64 + col];
          if (c < 32){
            const int e = c >> 3, q = c & 7;
            nat = atHu[(size_t)(base + min(s2 + e, nv-1))*8 + q];
          }
        }

        // layer0 for 4 edges: xs via b128 LDS loads; ea via composed 8-dot2
        float aXs[4] = {0,0,0,0}, aEa[4] = {0,0,0,0};
        #pragma unroll
        for (int i4 = 0; i4 < 4; ++i4){
          uint4 xsv[4];
          #pragma unroll
          for (int e = 0; e < 4; ++e)
            xsv[e] = *(const uint4*)&xsH[buf][e][t*16 + i4*4];
          const u32 wx0 = w0p[16+i4*4+0], wx1 = w0p[16+i4*4+1];
          const u32 wx2 = w0p[16+i4*4+2], wx3 = w0p[16+i4*4+3];
          #pragma unroll
          for (int e = 0; e < 4; ++e){
            aXs[e] = dot2f(xsv[e].x, wx0, aXs[e]);
            aXs[e] = dot2f(xsv[e].y, wx1, aXs[e]);
            aXs[e] = dot2f(xsv[e].z, wx2, aXs[e]);
            aXs[e] = dot2f(xsv[e].w, wx3, aXs[e]);
          }
        }
        #pragma unroll
        for (int i4 = 0; i4 < 2; ++i4){
          uint4 eav[4];
          #pragma unroll
          for (int e = 0; e < 4; ++e)
            eav[e] = *(const uint4*)&atS[buf][e][i4*4];
          const u32 we0 = wea[i4*4+0], we1 = wea[i4*4+1];
          const u32 we2 = wea[i4*4+2], we3 = wea[i4*4+3];
          #pragma unroll
          for (int e = 0; e < 4; ++e){
            aEa[e] = dot2f(eav[e].x, we0, aEa[e]);
            aEa[e] = dot2f(eav[e].y, we1, aEa[e]);
            aEa[e] = dot2f(eav[e].z, we2, aEa[e]);
            aEa[e] = dot2f(eav[e].w, we3, aEa[e]);
          }
        }
        // pack h pairwise (u32-typed store; even lanes write word (c, c+1))
        #pragma unroll
        for (int e = 0; e < 4; ++e){
          const float h = fmaxf(a0n + aXs[e] + aEa[e], 0.f);
          const u32 mine = (u32)f2h(h);
          const u32 oth  = (u32)__shfl_xor((int)mine, 1);
          if ((c & 1) == 0) hP[e][c >> 1] = mine | (oth << 16);
        }

        // layer1 for 4 edges (b128 hP loads; within-wave, no barrier needed)
        float mm[4] = {pb1, pb1, pb1, pb1};
        #pragma unroll
        for (int i4 = 0; i4 < 4; ++i4){
          uint4 hv[4];
          #pragma unroll
          for (int e = 0; e < 4; ++e) hv[e] = *(const uint4*)&hP[e][t*16 + i4*4];
          const u32 w0v = w1p[i4*4+0], w1v = w1p[i4*4+1];
          const u32 w2v = w1p[i4*4+2], w3v = w1p[i4*4+3];
          #pragma unroll
          for (int e = 0; e < 4; ++e){
            mm[e] = dot2f(hv[e].x, w0v, mm[e]);
            mm[e] = dot2f(hv[e].y, w1v, mm[e]);
            mm[e] = dot2f(hv[e].z, w2v, mm[e]);
            mm[e] = dot2f(hv[e].w, w3v, mm[e]);
          }
        }
        #pragma unroll
        for (int e = 0; e < 4; ++e){
          if (sub + e < nv){
            sum += mm[e]; sq = fmaf(mm[e], mm[e], sq);
            mn = fminf(mn, mm[e]); mx = fmaxf(mx, mm[e]);
          }
        }

        // write staged regs into the other buffer (no conflict with buf reads)
        if (hasNext){
          xsH[buf^1][el][col] = nxs0;
          xsH[buf^1][eh][col] = nxs1;
          if (c < 32){ const int e = c >> 3, q = c & 7; atS[buf^1][e][q] = nat; }
        }
        __syncthreads();               // single barrier per 4-edge group
      }
    }

    const int deg = e1 - e0;
    const size_t b = (size_t)n * 512;
    agg[b + c]       = sum;
    agg[b + 128 + c] = sq;
    agg[b + 256 + c] = (deg > 0) ? mn : 0.f;
    agg[b + 384 + c] = (deg > 0) ? mx : 0.f;
  }
}

// ======================= node phase: G=12 nodes/block, register-tiled =======================
__global__ __launch_bounds__(128, 2) void k_post(
  const float* __restrict__ x, const float* __restrict__ agg,
  const int* __restrict__ off,
  const float* __restrict__ postW0T, const float* __restrict__ postW1T,
  const float* __restrict__ WlinT,
  const float* __restrict__ post_b0, const float* __restrict__ post_b1,
  const float* __restrict__ b_lin, const float* __restrict__ ln_g,
  const float* __restrict__ ln_b,
  float* __restrict__ out)
{
  const int c = threadIdx.x;
  const int t = c >> 5;
  const int n0 = blockIdx.x * 12;

  __shared__ __align__(16) float aS[12][768];
  __shared__ __align__(16) float hpS[12][128];
  __shared__ __align__(16) float vS[12][128];
  __shared__ float s1S[12], s2S[12], muS[12], rsS[12];

  #pragma unroll
  for (int n = 0; n < 12; ++n){
    const size_t nb = (size_t)(n0 + n);
    aS[n][c] = x[nb*128 + c];
    float sum = agg[nb*512 + c];
    float sq  = agg[nb*512 + 128 + c];
    float mnv = agg[nb*512 + 256 + c];
    float mxv = agg[nb*512 + 384 + c];
    int deg = off[n0+n+1] - off[n0+n];
    float denom = fmaxf((float)deg, 1.f);
    float mean = sum / denom;
    float sd = sqrtf(fmaxf(sq/denom - mean*mean, 0.f) + 1e-5f);
    aS[n][128 + c] = sum;  aS[n][256 + c] = mean;
    aS[n][384 + c] = mnv;  aS[n][512 + c] = mxv;  aS[n][640 + c] = sd;
  }
  if (c < 12){
    int deg = off[n0+c+1] - off[n0+c];
    float logd = logf(fmaxf((float)deg, 1.f) + 1.f);
    s1S[c] = logd / ADL; s2S[c] = ADL / logd;
  }
  __syncthreads();

  float acc[12], pa1[12], pa2[12];
  const float pb0 = post_b0[c];
  #pragma unroll
  for (int n = 0; n < 12; ++n){ acc[n] = pb0; pa1[n] = 0.f; pa2[n] = 0.f; }
  const float* Wp = postW0T + (size_t)c * 512;
  #pragma unroll
  for (int k4 = 0; k4 < 8; ++k4){
    float4 w = *(const float4*)(Wp + k4*4);
    #pragma unroll
    for (int n = 0; n < 12; ++n){
      float4 a = *(const float4*)&aS[n][t*32 + k4*4];
      acc[n] = fmaf(a.x, w.x, acc[n]); acc[n] = fmaf(a.y, w.y, acc[n]);
      acc[n] = fmaf(a.z, w.z, acc[n]); acc[n] = fmaf(a.w, w.w, acc[n]);
    }
  }
  for (int a = 0; a < 5; ++a){
    #pragma unroll
    for (int k4 = 0; k4 < 8; ++k4){
      float4 w0v = *(const float4*)(Wp + 32  + a*32 + k4*4);
      float4 w1v = *(const float4*)(Wp + 192 + a*32 + k4*4);
      float4 w2v = *(const float4*)(Wp + 352 + a*32 + k4*4);
      #pragma unroll
      for (int n = 0; n < 12; ++n){
        float4 av = *(const float4*)&aS[n][128 + a*128 + t*32 + k4*4];
        acc[n] = fmaf(av.x, w0v.x, acc[n]); acc[n] = fmaf(av.y, w0v.y, acc[n]);
        acc[n] = fmaf(av.z, w0v.z, acc[n]); acc[n] = fmaf(av.w, w0v.w, acc[n]);
        pa1[n] = fmaf(av.x, w1v.x, pa1[n]); pa1[n] = fmaf(av.y, w1v.y, pa1[n]);
        pa1[n] = fmaf(av.z, w1v.z, pa1[n]); pa1[n] = fmaf(av.w, w1v.w, pa1[n]);
        pa2[n] = fmaf(av.x, w2v.x, pa2[n]); pa2[n] = fmaf(av.y, w2v.y, pa2[n]);
        pa2[n] = fmaf(av.z, w2v.z, pa2[n]); pa2[n] = fmaf(av.w, w2v.w, pa2[n]);
      }
    }
  }
  #pragma unroll
  for (int n = 0; n < 12; ++n)
    hpS[n][c] = fmaxf(acc[n] + s1S[n]*pa1[n] + s2S[n]*pa2[n], 0.f);
  __syncthreads();

  float w1r[32];
  #pragma unroll
  for (int q = 0; q < 8; ++q) *(float4*)&w1r[q*4] = *(const float4*)(postW1T + (size_t)c*32 + q*4);
  float a2[12];
  const float pb1v = post_b1[c];
  #pragma unroll
  for (int n = 0; n < 12; ++n) a2[n] = pb1v;
  #pragma unroll
  for (int g4 = 0; g4 < 8; ++g4){
    #pragma unroll
    for (int n = 0; n < 12; ++n){
      float4 h = *(const float4*)&hpS[n][t*32 + g4*4];
      a2[n] = fmaf(h.x, w1r[g4*4+0], a2[n]); a2[n] = fmaf(h.y, w1r[g4*4+1], a2[n]);
      a2[n] = fmaf(h.z, w1r[g4*4+2], a2[n]); a2[n] = fmaf(h.w, w1r[g4*4+3], a2[n]);
    }
  }
  #pragma unroll
  for (int n = 0; n < 12; ++n) vS[n][c] = a2[n];
  __syncthreads();

  float a3[12];
  const float blv = b_lin[c];
  #pragma unroll
  for (int n = 0; n < 12; ++n) a3[n] = blv;
  const float* Wl = WlinT + (size_t)c * 128;
  #pragma unroll 8
  for (int k4 = 0; k4 < 32; ++k4){
    float4 w = *(const float4*)(Wl + k4*4);
    #pragma unroll
    for (int n = 0; n < 12; ++n){
      float4 v = *(const float4*)&vS[n][k4*4];
      a3[n] = fmaf(v.x, w.x, a3[n]); a3[n] = fmaf(v.y, w.y, a3[n]);
      a3[n] = fmaf(v.z, w.z, a3[n]); a3[n] = fmaf(v.w, w.w, a3[n]);
    }
  }

  #pragma unroll
  for (int n = 0; n < 12; ++n) hpS[n][c] = a3[n];
  __syncthreads();
  {
    const int n = c >> 3, seg = c & 7;
    if (n < 12){
      float ps = 0.f, ps2 = 0.f;
      #pragma unroll
      for (int k = 0; k < 16; ++k){
        float v = hpS[n][seg*16 + k];
        ps += v; ps2 = fmaf(v, v, ps2);
      }
      ps += __shfl_xor(ps, 1); ps2 += __shfl_xor(ps2, 1);
      ps += __shfl_xor(ps, 2); ps2 += __shfl_xor(ps2, 2);
      ps += __shfl_xor(ps, 4); ps2 += __shfl_xor(ps2, 4);
      if (seg == 0){
        float mu = ps * (1.f/128.f);
        float var = fmaxf(ps2 * (1.f/128.f) - mu*mu, 0.f);
        muS[n] = mu; rsS[n] = rsqrtf(var + 1e-5f);
      }
    }
  }
  __syncthreads();
  const float gv = ln_g[c], bv = ln_b[c];
  #pragma unroll
  for (int n = 0; n < 12; ++n){
    float o = aS[n][c] + fmaxf((a3[n] - muS[n])*rsS[n]*gv + bv, 0.f);
    out[(size_t)(n0 + n)*128 + c] = o;
  }
}

// ======================= fallback: proven monolithic kernel (R3, f32) =======================
__global__ __launch_bounds__(128) void k_mono(
  const float* __restrict__ x, const int* __restrict__ ei,
  const float* __restrict__ eattr,
  const float* __restrict__ Wedge, const float* __restrict__ b_edge,
  const float* __restrict__ preW0, const float* __restrict__ pre_b0,
  const float* __restrict__ preW1, const float* __restrict__ pre_b1,
  const float* __restrict__ postW0, const float* __restrict__ post_b0,
  const float* __restrict__ postW1, const float* __restrict__ post_b1,
  const float* __restrict__ Wlin, const float* __restrict__ b_lin,
  const float* __restrict__ ln_g, const float* __restrict__ ln_b,
  const int* __restrict__ off, const int* __restrict__ eids,
  float* __restrict__ out)
{
  const int n = blockIdx.x;
  const int c = threadIdx.x;
  const int t = c >> 5, f = c & 31;
  __shared__ float xdS[128], xsS[128], eaS[32], hS[128];
  __shared__ float aggS[5][128], hpS[128], vS[128], red[4];

  const float xd = x[(size_t)n*128 + c];
  xdS[c] = xd;
  const int e0 = off[n], e1 = off[n+1];
  const int deg = e1 - e0;
  float sum = 0.f, sq = 0.f, mn = __builtin_inff(), mx = -__builtin_inff();
  __syncthreads();

  for (int idx = e0; idx < e1; ++idx){
    const int e = eids[idx];
    const int s = ei[e];
    xsS[c] = x[(size_t)s*128 + c];
    if (c < 32){
      float acc = b_edge[c];
      #pragma unroll
      for (int ii = 0; ii < 16; ++ii) acc = fmaf(eattr[(size_t)e*16 + ii], Wedge[ii*32 + c], acc);
      eaS[c] = acc;
    }
    __syncthreads();
    float acc = pre_b0[c];
    const float* W0 = preW0 + t*3072 + f;
    #pragma unroll 8
    for (int k = 0; k < 32; ++k) acc = fmaf(xdS[t*32+k], W0[k*32], acc);
    #pragma unroll 8
    for (int k = 0; k < 32; ++k) acc = fmaf(xsS[t*32+k], W0[(32+k)*32], acc);
    #pragma unroll 8
    for (int k = 0; k < 32; ++k) acc = fmaf(eaS[k], W0[(64+k)*32], acc);
    hS[c] = fmaxf(acc, 0.f);
    __syncthreads();
    float m = pre_b1[c];
    const float* W1 = preW1 + t*1024 + f;
    #pragma unroll 8
    for (int g = 0; g < 32; ++g) m = fmaf(hS[t*32+g], W1[g*32], m);
    sum += m; sq = fmaf(m, m, sq); mn = fminf(mn, m); mx = fmaxf(mx, m);
    __syncthreads();
  }
  const float d = (float)deg;
  const float denom = fmaxf(d, 1.f);
  const float mean = sum / denom;
  const float sd = sqrtf(fmaxf(sq/denom - mean*mean, 0.f) + 1e-5f);
  const float mnz = (deg > 0) ? mn : 0.f;
  const float mxz = (deg > 0) ? mx : 0.f;
  const float logd = logf(denom + 1.f);
  const float s1 = logd / ADL, s2 = ADL / logd;
  aggS[0][c] = sum; aggS[1][c] = mean; aggS[2][c] = mnz; aggS[3][c] = mxz; aggS[4][c] = sd;
  __syncthreads();
  float acc0 = post_b0[c];
  const float* P0 = postW0 + t*16384 + f;
  #pragma unroll 8
  for (int k = 0; k < 32; ++k) acc0 = fmaf(xdS[t*32+k], P0[k*32], acc0);
  float pa0 = 0.f, pa1 = 0.f, pa2 = 0.f;
  for (int a = 0; a < 5; ++a){
    const float* ag = &aggS[a][t*32];
    const float* Pb = P0 + (32 + a*32)*32;
    #pragma unroll 8
    for (int k = 0; k < 32; ++k){
      const float av = ag[k];
      pa0 = fmaf(av, Pb[k*32], pa0);
      pa1 = fmaf(av, Pb[(160+k)*32], pa1);
      pa2 = fmaf(av, Pb[(320+k)*32], pa2);
    }
  }
  hpS[c] = fmaxf(acc0 + pa0 + s1*pa1 + s2*pa2, 0.f);
  __syncthreads();
  float v = post_b1[c];
  const float* PW1 = postW1 + t*1024 + f;
  #pragma unroll 8
  for (int g = 0; g < 32; ++g) v = fmaf(hpS[t*32+g], PW1[g*32], v);
  vS[c] = v;
  __syncthreads();
  float l = b_lin[c];
  #pragma unroll 8
  for (int k = 0; k < 128; ++k) l = fmaf(vS[k], Wlin[k*128 + c], l);
  float ps = l, ps2 = l*l;
  #pragma unroll
  for (int o = 32; o >= 1; o >>= 1){ ps += __shfl_xor(ps, o); ps2 += __shfl_xor(ps2, o); }
  if ((c & 63) == 0){ red[c>>6] = ps; red[2 + (c>>6)] = ps2; }
  __syncthreads();
  const float mu = (red[0] + red[1]) * (1.f/128.f);
  const float var = fmaxf((red[2] + red[3]) * (1.f/128.f) - mu*mu, 0.f);
  const float rstd = rsqrtf(var + 1e-5f);
  out[(size_t)n*128 + c] = xd + fmaxf((l - mu)*rstd*ln_g[c] + ln_b[c], 0.f);
}

// ======================= launch =======================
extern "C" void kernel_launch(void* const* d_in, const int* in_sizes, int n_in,
                              void* d_out, int out_size, void* d_ws, size_t ws_size,
                              hipStream_t stream){
  const float* x       = (const float*)d_in[0];
  const int*   ei      = (const int*)d_in[1];
  const float* eattr   = (const float*)d_in[2];
  const float* Wedge   = (const float*)d_in[3];
  const float* b_edge  = (const float*)d_in[4];
  const float* preW0   = (const float*)d_in[5];
  const float* pre_b0  = (const float*)d_in[6];
  const float* preW1   = (const float*)d_in[7];
  const float* pre_b1  = (const float*)d_in[8];
  const float* postW0  = (const float*)d_in[9];
  const float* post_b0 = (const float*)d_in[10];
  const float* postW1  = (const float*)d_in[11];
  const float* post_b1 = (const float*)d_in[12];
  const float* Wlin    = (const float*)d_in[13];
  const float* b_lin   = (const float*)d_in[14];
  const float* ln_g    = (const float*)d_in[15];
  const float* ln_b    = (const float*)d_in[16];

  char* ws = (char*)d_ws;
  size_t o = 0;
  auto alloc = [&](size_t bytes)->char*{
    char* p = ws + o; o = (o + bytes + 255) & ~((size_t)255); return p;
  };
  int* off    = (int*)alloc((NN + 1) * 4);
  int* cnt    = (int*)alloc(NN * 4);
  int* cursor = (int*)alloc(NN * 4);
  int* eids   = (int*)alloc(NE * 4);
  int* sidc   = (int*)alloc(NE * 4);
  int* bsum   = (int*)alloc(32 * 4);
  u32* preW0H  = (u32*)alloc(4096 * 4);
  u32* preW1H  = (u32*)alloc(2048 * 4);
  float* postW0T = (float*)alloc(65536 * 4);
  float* postW1T = (float*)alloc(4096 * 4);
  float* WlinT   = (float*)alloc(16384 * 4);
  u16* eaM16   = (u16*)alloc(2048 * 2);
  float* pre_b0F = (float*)alloc(128 * 4);
  u32* eattrH  = (u32*)alloc((size_t)NE * 8 * 4);
  float* agg   = (float*)alloc((size_t)NN * 512 * 4);
  u32* xH      = (u32*)alloc((size_t)NN * 64 * 4);
  const size_t need = o;

  // CSR build
  hipMemsetAsync(cnt, 0, NN * 4, stream);
  hipMemsetAsync(cursor, 0, NN * 4, stream);
  k_hist<<<(NE + 255)/256, 256, 0, stream>>>(ei, cnt);
  k_scanA<<<30, 1024, 0, stream>>>(cnt, off, bsum);
  k_scanC<<<(NN + 256)/256, 256, 0, stream>>>(off, bsum);
  k_scatter<<<(NE + 255)/256, 256, 0, stream>>>(ei, eattr, off, cursor, eids, sidc, eattrH);

  if (ws_size < need){
    k_mono<<<NN, 128, 0, stream>>>(x, ei, eattr, Wedge, b_edge,
                                   preW0, pre_b0, preW1, pre_b1,
                                   postW0, post_b0, postW1, post_b1,
                                   Wlin, b_lin, ln_g, ln_b,
                                   off, eids, (float*)d_out);
    return;
  }

  k_prep<<<(NN*64 + 255)/256, 256, 0, stream>>>(x, preW0, preW1, postW0, postW1, Wlin,
                                                Wedge, b_edge, pre_b0,
                                                preW0H, preW1H, postW0T, postW1T, WlinT,
                                                eaM16, pre_b0F, xH);
  k_edge4<<<NN/8, 128, 0, stream>>>(xH, eattrH, sidc, preW0H, preW1H,
                                    (const u32*)eaM16, pre_b0F, pre_b1, off, agg);
  k_post<<<NN/12, 128, 0, stream>>>(x, agg, off, postW0T, postW1T, WlinT,
                                    post_b0, post_b1, b_lin, ln_g, ln_b,
                                    (float*)d_out);
}

// Round 18
// 362.824 us; speedup vs baseline: 3.1661x; 1.3112x over previous
//
#include <hip/hip_runtime.h>
#include <hip/hip_bf16.h>

#define NN 30000
#define NE 480000
#define ADL 2.8332133440562162f   // ln(17)

typedef unsigned int u32;
typedef unsigned short u16;

typedef _Float16 half2v __attribute__((ext_vector_type(2)));

__device__ __forceinline__ u16 f2h(float f){
  union { _Float16 h; u16 u; } v; v.h = (_Float16)f; return v.u;
}
__device__ __forceinline__ float h2f_lo(u32 u){
  union { u16 us; _Float16 h; } v; v.us = (u16)(u & 0xffff); return (float)v.h;
}
__device__ __forceinline__ float h2f_hi(u32 u){
  union { u16 us; _Float16 h; } v; v.us = (u16)(u >> 16); return (float)v.h;
}
__device__ __forceinline__ u32 pack2(float lo, float hi){
  return (u32)f2h(lo) | ((u32)f2h(hi) << 16);
}
__device__ __forceinline__ float dot2f(u32 a, u32 b, float c){
#if defined(__has_builtin) && __has_builtin(__builtin_amdgcn_fdot2)
  union U { u32 u; half2v h; };
  U ua, ub; ua.u = a; ub.u = b;
  return __builtin_amdgcn_fdot2(ua.h, ub.h, c, false);
#else
  float r;
  asm("v_dot2_f32_f16 %0, %1, %2, %3" : "=v"(r) : "v"(a), "v"(b), "v"(c));
  return r;
#endif
}

// ======================= CSR build =======================
__global__ void k_hist(const int* __restrict__ ei, int* __restrict__ cnt){
  int e = blockIdx.x * blockDim.x + threadIdx.x;
  if (e < NE) atomicAdd(&cnt[ei[NE + e]], 1);
}

__global__ __launch_bounds__(1024) void k_scanA(const int* __restrict__ cnt,
                                                int* __restrict__ off, int* __restrict__ bsum){
  __shared__ int buf[1024];
  const int b = blockIdx.x, tid = threadIdx.x;
  const int i = b*1024 + tid;
  int v = (i < NN) ? cnt[i] : 0;
  buf[tid] = v;
  __syncthreads();
  for (int s = 1; s < 1024; s <<= 1){
    int t = (tid >= s) ? buf[tid - s] : 0;
    __syncthreads();
    buf[tid] += t;
    __syncthreads();
  }
  if (i < NN) off[i] = buf[tid] - v;
  if (tid == 1023) bsum[b] = buf[1023];
}

__global__ void k_scanC(int* __restrict__ off, const int* __restrict__ bsum){
  int i = blockIdx.x * blockDim.x + threadIdx.x;
  if (i < NN){
    int pre = 0;
    const int nb = i >> 10;
    for (int b = 0; b < nb; ++b) pre += bsum[b];
    off[i] += pre;
  }
  if (i == NN) off[NN] = NE;
}

__global__ void k_scatter(const int* __restrict__ ei, const float* __restrict__ eattr,
                          const int* __restrict__ off,
                          int* __restrict__ cursor, int* __restrict__ eids,
                          int* __restrict__ sidC, u32* __restrict__ eattrH){
  int e = blockIdx.x * blockDim.x + threadIdx.x;
  if (e < NE){
    int d = ei[NE + e];
    int pos = off[d] + atomicAdd(&cursor[d], 1);
    eids[pos] = e;
    sidC[pos] = ei[e];
    const float* ar = eattr + (size_t)e * 16;
    u32* dst = eattrH + (size_t)pos * 8;
    #pragma unroll
    for (int q = 0; q < 8; ++q) dst[q] = pack2(ar[2*q], ar[2*q+1]);
  }
}

// ======================= prep: f16 weight packs + x pre-pack + composed ea matrix =======================
__global__ void k_prep(const float* __restrict__ x,
                       const float* __restrict__ preW0, const float* __restrict__ preW1,
                       const float* __restrict__ postW0, const float* __restrict__ postW1,
                       const float* __restrict__ Wlin,
                       const float* __restrict__ Wedge, const float* __restrict__ b_edge,
                       const float* __restrict__ pre_b0,
                       u32* __restrict__ preW0H, u32* __restrict__ preW1H,
                       u32* __restrict__ postW0H, u32* __restrict__ postW1H,
                       u32* __restrict__ WlinH,
                       u16* __restrict__ eaM16, float* __restrict__ pre_b0F,
                       u32* __restrict__ xH)
{
  int i = blockIdx.x * blockDim.x + threadIdx.x;
  if (i < NN * 64){                       // x pre-pack (f32 -> half2)
    const float2 v = *(const float2*)(x + (size_t)i * 2);
    xH[i] = pack2(v.x, v.y);
  }
  if (i < 32768){                         // postW0H[c][q]: pair (k=2q,2q+1) of postW0[t][k][f]
    int c = i >> 8, q = i & 255;
    int t = c >> 5, f = c & 31;
    postW0H[i] = pack2(postW0[t*16384 + (2*q)*32 + f], postW0[t*16384 + (2*q+1)*32 + f]);
  }
  if (i < 8192){                          // WlinH[c][q]: pair (k=2q,2q+1) of Wlin[k][c]
    int c = i >> 6, q = i & 63;
    WlinH[i] = pack2(Wlin[(2*q)*128 + c], Wlin[(2*q+1)*128 + c]);
  }
  if (i < 4096){                          // preW0H[c][q]: xd+xs pairs only (k=0..63)
    int c = i >> 5, q = i & 31;
    int t = c >> 5, f = c & 31;
    preW0H[i] = pack2(preW0[t*3072 + (2*q)*32 + f], preW0[t*3072 + (2*q+1)*32 + f]);
  }
  if (i < 2048){                          // preW1H[c][q]
    int c = i >> 4, q = i & 15;
    int t = c >> 5, f = c & 31;
    preW1H[i] = pack2(preW1[t*1024 + (2*q)*32 + f], preW1[t*1024 + (2*q+1)*32 + f]);
  }
  if (i < 2048){                          // postW1H[c][q]
    int c = i >> 4, q = i & 15;
    int t = c >> 5, f = c & 31;
    postW1H[i] = pack2(postW1[t*1024 + (2*q)*32 + f], postW1[t*1024 + (2*q+1)*32 + f]);
  }
  if (i < 2048){                          // composed M[kk][c] = sum_g Wedge[kk][g]*W0ea[t][g][f]
    int c = i >> 4, kk = i & 15;
    int t = c >> 5, f = c & 31;
    float acc = 0.f;
    #pragma unroll 8
    for (int g = 0; g < 32; ++g)
      acc = fmaf(Wedge[kk*32 + g], preW0[t*3072 + (64+g)*32 + f], acc);
    eaM16[c*16 + kk] = f2h(acc);
  }
  if (i < 128){                           // pre_b0F[c] = pre_b0[c] + b_edge . W0ea[:,c]
    int t = i >> 5, f = i & 31;
    float acc = pre_b0[i];
    #pragma unroll 8
    for (int g = 0; g < 32; ++g)
      acc = fmaf(b_edge[g], preW0[t*3072 + (64+g)*32 + f], acc);
    pre_b0F[i] = acc;
  }
}

// ======================= edge phase (R17-proven; agg output now f16-packed) =======================
__global__ __launch_bounds__(128, 2) void k_edge4(
  const u32* __restrict__ xHu,
  const u32* __restrict__ atHu,
  const int* __restrict__ sidC,
  const u32* __restrict__ preW0H, const u32* __restrict__ preW1H,
  const u32* __restrict__ eaMu,
  const float* __restrict__ pre_b0F, const float* __restrict__ pre_b1,
  const int* __restrict__ off,
  u32* __restrict__ aggP)
{
  const int c = threadIdx.x;        // channel 0..127
  const int t = c >> 5;             // tower

  __shared__ __align__(16) u32 xdH[64];
  __shared__ __align__(16) u32 xsH[2][4][64];
  __shared__ __align__(16) u32 atS[2][4][8];
  __shared__ __align__(16) u32 hP[4][64];
  __shared__ int sidS[64];

  u32 w0p[32], w1p[16], wea[8];
  #pragma unroll
  for (int q = 0; q < 8; ++q) *(uint4*)&w0p[q*4] = *(const uint4*)(preW0H + (size_t)c*32 + q*4);
  #pragma unroll
  for (int q = 0; q < 4; ++q) *(uint4*)&w1p[q*4] = *(const uint4*)(preW1H + (size_t)c*16 + q*4);
  #pragma unroll
  for (int q = 0; q < 2; ++q) *(uint4*)&wea[q*4] = *(const uint4*)(eaMu + (size_t)c*8 + q*4);
  const float pb0 = pre_b0F[c];
  const float pb1 = pre_b1[c];

  const int el = c >> 6;
  const int eh = el + 2;
  const int col = c & 63;

  for (int nn = 0; nn < 8; ++nn){
    const int n = blockIdx.x * 8 + nn;
    __syncthreads();
    if (c < 64) xdH[c] = xHu[(size_t)n*64 + c];
    const int e0 = off[n], e1 = off[n+1];
    float sum = 0.f, sq = 0.f;
    float mn = __builtin_inff(), mx = -__builtin_inff();

    for (int base = e0; base < e1; base += 64){
      const int nv = min(64, e1 - base);
      if (c < nv) sidS[c] = sidC[base + c];
      __syncthreads();

      float a0n = pb0;
      #pragma unroll
      for (int i4 = 0; i4 < 4; ++i4){
        const uint4 xv = *(const uint4*)&xdH[t*16 + i4*4];
        a0n = dot2f(xv.x, w0p[i4*4+0], a0n);
        a0n = dot2f(xv.y, w0p[i4*4+1], a0n);
        a0n = dot2f(xv.z, w0p[i4*4+2], a0n);
        a0n = dot2f(xv.w, w0p[i4*4+3], a0n);
      }

      const int np = (nv + 3) >> 2;

      {
        const int g0 = min(el, nv-1), g1 = min(eh, nv-1);
        xsH[0][el][col] = xHu[(size_t)sidS[g0]*64 + col];
        xsH[0][eh][col] = xHu[(size_t)sidS[g1]*64 + col];
        if (c < 32){
          const int e = c >> 3, q = c & 7;
          atS[0][e][q] = atHu[(size_t)(base + min(e, nv-1))*8 + q];
        }
      }
      __syncthreads();

      for (int p = 0; p < np; ++p){
        const int buf = p & 1;
        const int sub = p * 4;
        const bool hasNext = (p + 1 < np);

        u32 nxs0 = 0, nxs1 = 0, nat = 0;
        if (hasNext){
          const int s2 = sub + 4;
          const int g0 = min(s2 + el, nv-1), g1 = min(s2 + eh, nv-1);
          nxs0 = xHu[(size_t)sidS[g0]*64 + col];
          nxs1 = xHu[(size_t)sidS[g1]*64 + col];
          if (c < 32){
            const int e = c >> 3, q = c & 7;
            nat = atHu[(size_t)(base + min(s2 + e, nv-1))*8 + q];
          }
        }

        float aXs[4] = {0,0,0,0}, aEa[4] = {0,0,0,0};
        #pragma unroll
        for (int i4 = 0; i4 < 4; ++i4){
          uint4 xsv[4];
          #pragma unroll
          for (int e = 0; e < 4; ++e)
            xsv[e] = *(const uint4*)&xsH[buf][e][t*16 + i4*4];
          const u32 wx0 = w0p[16+i4*4+0], wx1 = w0p[16+i4*4+1];
          const u32 wx2 = w0p[16+i4*4+2], wx3 = w0p[16+i4*4+3];
          #pragma unroll
          for (int e = 0; e < 4; ++e){
            aXs[e] = dot2f(xsv[e].x, wx0, aXs[e]);
            aXs[e] = dot2f(xsv[e].y, wx1, aXs[e]);
            aXs[e] = dot2f(xsv[e].z, wx2, aXs[e]);
            aXs[e] = dot2f(xsv[e].w, wx3, aXs[e]);
          }
        }
        #pragma unroll
        for (int i4 = 0; i4 < 2; ++i4){
          uint4 eav[4];
          #pragma unroll
          for (int e = 0; e < 4; ++e)
            eav[e] = *(const uint4*)&atS[buf][e][i4*4];
          const u32 we0 = wea[i4*4+0], we1 = wea[i4*4+1];
          const u32 we2 = wea[i4*4+2], we3 = wea[i4*4+3];
          #pragma unroll
          for (int e = 0; e < 4; ++e){
            aEa[e] = dot2f(eav[e].x, we0, aEa[e]);
            aEa[e] = dot2f(eav[e].y, we1, aEa[e]);
            aEa[e] = dot2f(eav[e].z, we2, aEa[e]);
            aEa[e] = dot2f(eav[e].w, we3, aEa[e]);
          }
        }
        #pragma unroll
        for (int e = 0; e < 4; ++e){
          const float h = fmaxf(a0n + aXs[e] + aEa[e], 0.f);
          const u32 mine = (u32)f2h(h);
          const u32 oth  = (u32)__shfl_xor((int)mine, 1);
          if ((c & 1) == 0) hP[e][c >> 1] = mine | (oth << 16);
        }

        float mm[4] = {pb1, pb1, pb1, pb1};
        #pragma unroll
        for (int i4 = 0; i4 < 4; ++i4){
          uint4 hv[4];
          #pragma unroll
          for (int e = 0; e < 4; ++e) hv[e] = *(const uint4*)&hP[e][t*16 + i4*4];
          const u32 w0v = w1p[i4*4+0], w1v = w1p[i4*4+1];
          const u32 w2v = w1p[i4*4+2], w3v = w1p[i4*4+3];
          #pragma unroll
          for (int e = 0; e < 4; ++e){
            mm[e] = dot2f(hv[e].x, w0v, mm[e]);
            mm[e] = dot2f(hv[e].y, w1v, mm[e]);
            mm[e] = dot2f(hv[e].z, w2v, mm[e]);
            mm[e] = dot2f(hv[e].w, w3v, mm[e]);
          }
        }
        #pragma unroll
        for (int e = 0; e < 4; ++e){
          if (sub + e < nv){
            sum += mm[e]; sq = fmaf(mm[e], mm[e], sq);
            mn = fminf(mn, mm[e]); mx = fmaxf(mx, mm[e]);
          }
        }

        if (hasNext){
          xsH[buf^1][el][col] = nxs0;
          xsH[buf^1][eh][col] = nxs1;
          if (c < 32){ const int e = c >> 3, q = c & 7; atS[buf^1][e][q] = nat; }
        }
        __syncthreads();
      }
    }

    const int deg = e1 - e0;
    const float mnz = (deg > 0) ? mn : 0.f;
    const float mxz = (deg > 0) ? mx : 0.f;
    // pack agg pairs (f16) via lane-partner shfl; even lanes store u32
    const u32 sm = (u32)f2h(sum),  so = (u32)__shfl_xor((int)sm, 1);
    const u32 qm = (u32)f2h(sq),   qo = (u32)__shfl_xor((int)qm, 1);
    const u32 nm = (u32)f2h(mnz),  no = (u32)__shfl_xor((int)nm, 1);
    const u32 xm = (u32)f2h(mxz),  xo = (u32)__shfl_xor((int)xm, 1);
    if ((c & 1) == 0){
      const size_t b = (size_t)n * 256;
      const int j = c >> 1;
      aggP[b + j]        = sm | (so << 16);
      aggP[b + 64 + j]   = qm | (qo << 16);
      aggP[b + 128 + j]  = nm | (no << 16);
      aggP[b + 192 + j]  = xm | (xo << 16);
    }
  }
}

// ======================= node phase v2: f16 dot2 datapath, packed LDS =======================
// R17: k_post 240us @ VALU 30%, occupancy 15% (49.7KB LDS). f16 packing halves VALU ops,
// LDS (->~31KB, 5 blk/CU), weight L2 traffic, and agg read bytes.
__global__ __launch_bounds__(128, 2) void k_post2(
  const float* __restrict__ x, const u32* __restrict__ xHu,
  const u32* __restrict__ aggP,
  const int* __restrict__ off,
  const u32* __restrict__ postW0H, const u32* __restrict__ postW1H,
  const u32* __restrict__ WlinH,
  const float* __restrict__ post_b0, const float* __restrict__ post_b1,
  const float* __restrict__ b_lin, const float* __restrict__ ln_g,
  const float* __restrict__ ln_b,
  float* __restrict__ out)
{
  const int c = threadIdx.x;
  const int t = c >> 5;
  const int n0 = blockIdx.x * 12;

  __shared__ __align__(16) u32 aS[12][384];   // [xd(64) | sum | mean | mn | mx | sd] pairs
  __shared__ __align__(16) u32 hpP[12][64];
  __shared__ __align__(16) u32 vP[12][64];
  __shared__ __align__(16) float lnS[12][128];
  __shared__ float s1S[12], s2S[12], muS[12], rsS[12];

  // stage: xd pairs + agg pairs (mean/sd computed here)
  {
    const int half = c >> 6, j = c & 63;
    #pragma unroll
    for (int k = 0; k < 6; ++k){
      const int n = half + k*2;
      const size_t nb = (size_t)(n0 + n);
      aS[n][j] = xHu[nb*64 + j];
      const u32 sp = aggP[nb*256 + j];
      const u32 qp = aggP[nb*256 + 64 + j];
      const int deg = off[n0+n+1] - off[n0+n];
      const float denom = fmaxf((float)deg, 1.f);
      const float s0 = h2f_lo(sp), s1v = h2f_hi(sp);
      const float q0 = h2f_lo(qp), q1v = h2f_hi(qp);
      const float me0 = s0 / denom, me1 = s1v / denom;
      const float sd0 = sqrtf(fmaxf(q0/denom - me0*me0, 0.f) + 1e-5f);
      const float sd1 = sqrtf(fmaxf(q1v/denom - me1*me1, 0.f) + 1e-5f);
      aS[n][64 + j]  = sp;                       // sum pairs as-is
      aS[n][128 + j] = pack2(me0, me1);          // mean
      aS[n][192 + j] = aggP[nb*256 + 128 + j];   // mn
      aS[n][256 + j] = aggP[nb*256 + 192 + j];   // mx
      aS[n][320 + j] = pack2(sd0, sd1);          // sd
    }
  }
  if (c < 12){
    int deg = off[n0+c+1] - off[n0+c];
    float logd = logf(fmaxf((float)deg, 1.f) + 1.f);
    s1S[c] = logd / ADL; s2S[c] = ADL / logd;
  }
  __syncthreads();

  // ---- post layer0: dot2, weight pairs streamed from L2 (128KB, reused x12 nodes)
  float acc[12], pa1[12], pa2[12];
  const float pb0 = post_b0[c];
  #pragma unroll
  for (int n = 0; n < 12; ++n){ acc[n] = pb0; pa1[n] = 0.f; pa2[n] = 0.f; }
  const u32* Wp = postW0H + (size_t)c * 256;
  #pragma unroll
  for (int q4 = 0; q4 < 4; ++q4){          // xt pairs (0..15)
    const uint4 w = *(const uint4*)(Wp + q4*4);
    #pragma unroll
    for (int n = 0; n < 12; ++n){
      const uint4 av = *(const uint4*)&aS[n][t*16 + q4*4];
      acc[n] = dot2f(av.x, w.x, acc[n]); acc[n] = dot2f(av.y, w.y, acc[n]);
      acc[n] = dot2f(av.z, w.z, acc[n]); acc[n] = dot2f(av.w, w.w, acc[n]);
    }
  }
  for (int a = 0; a < 5; ++a){
    #pragma unroll
    for (int q4 = 0; q4 < 4; ++q4){
      const uint4 wI = *(const uint4*)(Wp + 16  + a*16 + q4*4);
      const uint4 wA = *(const uint4*)(Wp + 96  + a*16 + q4*4);
      const uint4 wT = *(const uint4*)(Wp + 176 + a*16 + q4*4);
      #pragma unroll
      for (int n = 0; n < 12; ++n){
        const uint4 av = *(const uint4*)&aS[n][64 + a*64 + t*16 + q4*4];
        acc[n] = dot2f(av.x, wI.x, acc[n]); acc[n] = dot2f(av.y, wI.y, acc[n]);
        acc[n] = dot2f(av.z, wI.z, acc[n]); acc[n] = dot2f(av.w, wI.w, acc[n]);
        pa1[n] = dot2f(av.x, wA.x, pa1[n]); pa1[n] = dot2f(av.y, wA.y, pa1[n]);
        pa1[n] = dot2f(av.z, wA.z, pa1[n]); pa1[n] = dot2f(av.w, wA.w, pa1[n]);
        pa2[n] = dot2f(av.x, wT.x, pa2[n]); pa2[n] = dot2f(av.y, wT.y, pa2[n]);
        pa2[n] = dot2f(av.z, wT.z, pa2[n]); pa2[n] = dot2f(av.w, wT.w, pa2[n]);
      }
    }
  }
  #pragma unroll
  for (int n = 0; n < 12; ++n){
    const float hp = fmaxf(acc[n] + s1S[n]*pa1[n] + s2S[n]*pa2[n], 0.f);
    const u32 mine = (u32)f2h(hp);
    const u32 oth  = (u32)__shfl_xor((int)mine, 1);
    if ((c & 1) == 0) hpP[n][c >> 1] = mine | (oth << 16);
  }
  __syncthreads();

  // ---- post layer1 (dot2, weights in regs)
  u32 w1p2[16];
  #pragma unroll
  for (int q = 0; q < 4; ++q) *(uint4*)&w1p2[q*4] = *(const uint4*)(postW1H + (size_t)c*16 + q*4);
  const float pb1v = post_b1[c];
  #pragma unroll
  for (int n = 0; n < 12; ++n){
    float a2 = pb1v;
    #pragma unroll
    for (int q4 = 0; q4 < 4; ++q4){
      const uint4 hv = *(const uint4*)&hpP[n][t*16 + q4*4];
      a2 = dot2f(hv.x, w1p2[q4*4+0], a2); a2 = dot2f(hv.y, w1p2[q4*4+1], a2);
      a2 = dot2f(hv.z, w1p2[q4*4+2], a2); a2 = dot2f(hv.w, w1p2[q4*4+3], a2);
    }
    const u32 mine = (u32)f2h(a2);
    const u32 oth  = (u32)__shfl_xor((int)mine, 1);
    if ((c & 1) == 0) vP[n][c >> 1] = mine | (oth << 16);
  }
  __syncthreads();

  // ---- final linear H->H (dot2; WlinH 32KB from L2, reused x12)
  float a3[12];
  const float blv = b_lin[c];
  #pragma unroll
  for (int n = 0; n < 12; ++n) a3[n] = blv;
  const u32* Wl = WlinH + (size_t)c * 64;
  #pragma unroll 4
  for (int q4 = 0; q4 < 16; ++q4){
    const uint4 w = *(const uint4*)(Wl + q4*4);
    #pragma unroll
    for (int n = 0; n < 12; ++n){
      const uint4 vv = *(const uint4*)&vP[n][q4*4];
      a3[n] = dot2f(vv.x, w.x, a3[n]); a3[n] = dot2f(vv.y, w.y, a3[n]);
      a3[n] = dot2f(vv.z, w.z, a3[n]); a3[n] = dot2f(vv.w, w.w, a3[n]);
    }
  }

  // ---- LayerNorm (f32)
  #pragma unroll
  for (int n = 0; n < 12; ++n) lnS[n][c] = a3[n];
  __syncthreads();
  {
    const int n = c >> 3, seg = c & 7;
    if (n < 12){
      float ps = 0.f, ps2 = 0.f;
      #pragma unroll
      for (int k = 0; k < 16; ++k){
        float v = lnS[n][seg*16 + k];
        ps += v; ps2 = fmaf(v, v, ps2);
      }
      ps += __shfl_xor(ps, 1); ps2 += __shfl_xor(ps2, 1);
      ps += __shfl_xor(ps, 2); ps2 += __shfl_xor(ps2, 2);
      ps += __shfl_xor(ps, 4); ps2 += __shfl_xor(ps2, 4);
      if (seg == 0){
        float mu = ps * (1.f/128.f);
        float var = fmaxf(ps2 * (1.f/128.f) - mu*mu, 0.f);
        muS[n] = mu; rsS[n] = rsqrtf(var + 1e-5f);
      }
    }
  }
  __syncthreads();
  const float gv = ln_g[c], bv = ln_b[c];
  #pragma unroll
  for (int n = 0; n < 12; ++n){
    const size_t nb = (size_t)(n0 + n);
    float o = x[nb*128 + c] + fmaxf((a3[n] - muS[n])*rsS[n]*gv + bv, 0.f);
    out[nb*128 + c] = o;
  }
}

// ======================= fallback: proven monolithic kernel (R3, f32) =======================
__global__ __launch_bounds__(128) void k_mono(
  const float* __restrict__ x, const int* __restrict__ ei,
  const float* __restrict__ eattr,
  const float* __restrict__ Wedge, const float* __restrict__ b_edge,
  const float* __restrict__ preW0, const float* __restrict__ pre_b0,
  const float* __restrict__ preW1, const float* __restrict__ pre_b1,
  const float* __restrict__ postW0, const float* __restrict__ post_b0,
  const float* __restrict__ postW1, const float* __restrict__ post_b1,
  const float* __restrict__ Wlin, const float* __restrict__ b_lin,
  const float* __restrict__ ln_g, const float* __restrict__ ln_b,
  const int* __restrict__ off, const int* __restrict__ eids,
  float* __restrict__ out)
{
  const int n = blockIdx.x;
  const int c = threadIdx.x;
  const int t = c >> 5, f = c & 31;
  __shared__ float xdS[128], xsS[128], eaS[32], hS[128];
  __shared__ float aggS[5][128], hpS[128], vS[128], red[4];

  const float xd = x[(size_t)n*128 + c];
  xdS[c] = xd;
  const int e0 = off[n], e1 = off[n+1];
  const int deg = e1 - e0;
  float sum = 0.f, sq = 0.f, mn = __builtin_inff(), mx = -__builtin_inff();
  __syncthreads();

  for (int idx = e0; idx < e1; ++idx){
    const int e = eids[idx];
    const int s = ei[e];
    xsS[c] = x[(size_t)s*128 + c];
    if (c < 32){
      float acc = b_edge[c];
      #pragma unroll
      for (int ii = 0; ii < 16; ++ii) acc = fmaf(eattr[(size_t)e*16 + ii], Wedge[ii*32 + c], acc);
      eaS[c] = acc;
    }
    __syncthreads();
    float acc = pre_b0[c];
    const float* W0 = preW0 + t*3072 + f;
    #pragma unroll 8
    for (int k = 0; k < 32; ++k) acc = fmaf(xdS[t*32+k], W0[k*32], acc);
    #pragma unroll 8
    for (int k = 0; k < 32; ++k) acc = fmaf(xsS[t*32+k], W0[(32+k)*32], acc);
    #pragma unroll 8
    for (int k = 0; k < 32; ++k) acc = fmaf(eaS[k], W0[(64+k)*32], acc);
    hS[c] = fmaxf(acc, 0.f);
    __syncthreads();
    float m = pre_b1[c];
    const float* W1 = preW1 + t*1024 + f;
    #pragma unroll 8
    for (int g = 0; g < 32; ++g) m = fmaf(hS[t*32+g], W1[g*32], m);
    sum += m; sq = fmaf(m, m, sq); mn = fminf(mn, m); mx = fmaxf(mx, m);
    __syncthreads();
  }
  const float d = (float)deg;
  const float denom = fmaxf(d, 1.f);
  const float mean = sum / denom;
  const float sd = sqrtf(fmaxf(sq/denom - mean*mean, 0.f) + 1e-5f);
  const float mnz = (deg > 0) ? mn : 0.f;
  const float mxz = (deg > 0) ? mx : 0.f;
  const float logd = logf(denom + 1.f);
  const float s1 = logd / ADL, s2 = ADL / logd;
  aggS[0][c] = sum; aggS[1][c] = mean; aggS[2][c] = mnz; aggS[3][c] = mxz; aggS[4][c] = sd;
  __syncthreads();
  float acc0 = post_b0[c];
  const float* P0 = postW0 + t*16384 + f;
  #pragma unroll 8
  for (int k = 0; k < 32; ++k) acc0 = fmaf(xdS[t*32+k], P0[k*32], acc0);
  float pa0 = 0.f, pa1 = 0.f, pa2 = 0.f;
  for (int a = 0; a < 5; ++a){
    const float* ag = &aggS[a][t*32];
    const float* Pb = P0 + (32 + a*32)*32;
    #pragma unroll 8
    for (int k = 0; k < 32; ++k){
      const float av = ag[k];
      pa0 = fmaf(av, Pb[k*32], pa0);
      pa1 = fmaf(av, Pb[(160+k)*32], pa1);
      pa2 = fmaf(av, Pb[(320+k)*32], pa2);
    }
  }
  hpS[c] = fmaxf(acc0 + pa0 + s1*pa1 + s2*pa2, 0.f);
  __syncthreads();
  float v = post_b1[c];
  const float* PW1 = postW1 + t*1024 + f;
  #pragma unroll 8
  for (int g = 0; g < 32; ++g) v = fmaf(hpS[t*32+g], PW1[g*32], v);
  vS[c] = v;
  __syncthreads();
  float l = b_lin[c];
  #pragma unroll 8
  for (int k = 0; k < 128; ++k) l = fmaf(vS[k], Wlin[k*128 + c], l);
  float ps = l, ps2 = l*l;
  #pragma unroll
  for (int o = 32; o >= 1; o >>= 1){ ps += __shfl_xor(ps, o); ps2 += __shfl_xor(ps2, o); }
  if ((c & 63) == 0){ red[c>>6] = ps; red[2 + (c>>6)] = ps2; }
  __syncthreads();
  const float mu = (red[0] + red[1]) * (1.f/128.f);
  const float var = fmaxf((red[2] + red[3]) * (1.f/128.f) - mu*mu, 0.f);
  const float rstd = rsqrtf(var + 1e-5f);
  out[(size_t)n*128 + c] = xd + fmaxf((l - mu)*rstd*ln_g[c] + ln_b[c], 0.f);
}

// ======================= launch =======================
extern "C" void kernel_launch(void* const* d_in, const int* in_sizes, int n_in,
                              void* d_out, int out_size, void* d_ws, size_t ws_size,
                              hipStream_t stream){
  const float* x       = (const float*)d_in[0];
  const int*   ei      = (const int*)d_in[1];
  const float* eattr   = (const float*)d_in[2];
  const float* Wedge   = (const float*)d_in[3];
  const float* b_edge  = (const float*)d_in[4];
  const float* preW0   = (const float*)d_in[5];
  const float* pre_b0  = (const float*)d_in[6];
  const float* preW1   = (const float*)d_in[7];
  const float* pre_b1  = (const float*)d_in[8];
  const float* postW0  = (const float*)d_in[9];
  const float* post_b0 = (const float*)d_in[10];
  const float* postW1  = (const float*)d_in[11];
  const float* post_b1 = (const float*)d_in[12];
  const float* Wlin    = (const float*)d_in[13];
  const float* b_lin   = (const float*)d_in[14];
  const float* ln_g    = (const float*)d_in[15];
  const float* ln_b    = (const float*)d_in[16];

  char* ws = (char*)d_ws;
  size_t o = 0;
  auto alloc = [&](size_t bytes)->char*{
    char* p = ws + o; o = (o + bytes + 255) & ~((size_t)255); return p;
  };
  int* off    = (int*)alloc((NN + 1) * 4);
  int* cnt    = (int*)alloc(NN * 4);
  int* cursor = (int*)alloc(NN * 4);
  int* eids   = (int*)alloc(NE * 4);
  int* sidc   = (int*)alloc(NE * 4);
  int* bsum   = (int*)alloc(32 * 4);
  u32* preW0H  = (u32*)alloc(4096 * 4);
  u32* preW1H  = (u32*)alloc(2048 * 4);
  u32* postW0H = (u32*)alloc(32768 * 4);
  u32* postW1H = (u32*)alloc(2048 * 4);
  u32* WlinH   = (u32*)alloc(8192 * 4);
  u16* eaM16   = (u16*)alloc(2048 * 2);
  float* pre_b0F = (float*)alloc(128 * 4);
  u32* eattrH  = (u32*)alloc((size_t)NE * 8 * 4);
  u32* aggP    = (u32*)alloc((size_t)NN * 256 * 4);
  u32* xH      = (u32*)alloc((size_t)NN * 64 * 4);
  const size_t need = o;

  // CSR build
  hipMemsetAsync(cnt, 0, NN * 4, stream);
  hipMemsetAsync(cursor, 0, NN * 4, stream);
  k_hist<<<(NE + 255)/256, 256, 0, stream>>>(ei, cnt);
  k_scanA<<<30, 1024, 0, stream>>>(cnt, off, bsum);
  k_scanC<<<(NN + 256)/256, 256, 0, stream>>>(off, bsum);
  k_scatter<<<(NE + 255)/256, 256, 0, stream>>>(ei, eattr, off, cursor, eids, sidc, eattrH);

  if (ws_size < need){
    k_mono<<<NN, 128, 0, stream>>>(x, ei, eattr, Wedge, b_edge,
                                   preW0, pre_b0, preW1, pre_b1,
                                   postW0, post_b0, postW1, post_b1,
                                   Wlin, b_lin, ln_g, ln_b,
                                   off, eids, (float*)d_out);
    return;
  }

  k_prep<<<(NN*64 + 255)/256, 256, 0, stream>>>(x, preW0, preW1, postW0, postW1, Wlin,
                                                Wedge, b_edge, pre_b0,
                                                preW0H, preW1H, postW0H, postW1H, WlinH,
                                                eaM16, pre_b0F, xH);
  k_edge4<<<NN/8, 128, 0, stream>>>(xH, eattrH, sidc, preW0H, preW1H,
                                    (const u32*)eaM16, pre_b0F, pre_b1, off, aggP);
  k_post2<<<NN/12, 128, 0, stream>>>(x, xH, aggP, off, postW0H, postW1H, WlinH,
                                     post_b0, post_b1, b_lin, ln_g, ln_b,
                                     (float*)d_out);
}